// Round 7
// baseline (6399.665 us; speedup 1.0000x reference)
//
#include <hip/hip_runtime.h>

constexpr int PTS = 2048;   // points per batch
constexpr int KK  = 20;     // knn

typedef __attribute__((ext_vector_type(8))) short bf8;
typedef __attribute__((ext_vector_type(4))) float f32x4;

static __device__ __forceinline__ float lrelu(float x) { return fmaxf(x, 0.2f * x); }
static __device__ __forceinline__ float rl(float v, int l) {
  return __int_as_float(__builtin_amdgcn_readlane(__float_as_int(v), l));
}
static __device__ __forceinline__ unsigned cvt2(float lo, float hi) {
  unsigned r;
  asm("v_cvt_pk_bf16_f32 %0, %1, %2" : "=v"(r) : "v"(lo), "v"(hi));
  return r;
}
// residual after bf16-hi extraction: packs bf16(a - hi(a)), bf16(b - hi(b))
static __device__ __forceinline__ unsigned cvt2lo(float a, float b, unsigned h) {
  return cvt2(a - __uint_as_float(h << 16), b - __uint_as_float(h & 0xffff0000u));
}
static __device__ __forceinline__ unsigned short rne_bf16(float v) {
  unsigned u = __float_as_uint(v);
  return (unsigned short)((u + 0x7fffu + ((u >> 16) & 1u)) >> 16);
}
static __device__ __forceinline__ float bf2f(unsigned short u) {
  return __uint_as_float(((unsigned)u) << 16);
}
static __device__ __forceinline__ int swz(int row, int slot) {
  return slot ^ (row & 3) ^ ((row >> 2) & 3);   // 16B-slot swizzle, conflict-free
}
static __device__ __forceinline__ void argmax64(float& v, int& m) {
#pragma unroll
  for (int mask = 1; mask < 64; mask <<= 1) {
    float ov = __shfl_xor(v, mask, 64);
    int om = __shfl_xor(m, mask, 64);
    if (ov > v || (ov == v && om < m)) { v = ov; m = om; }
  }
}

// ---------------- xx[b][m] = sum_c x[c][m]^2 ----------------
template <int C>
__global__ __launch_bounds__(256) void xnorm_k(const float* __restrict__ x, float* __restrict__ xx) {
  const int i = blockIdx.x * 256 + threadIdx.x;
  const int b = i >> 11, m = i & 2047;
  float s = 0.f;
#pragma unroll
  for (int c = 0; c < C; ++c) {
    const float v = x[((long long)b * C + c) * PTS + m];
    s = fmaf(v, v, s);
  }
  xx[i] = s;
}

// ---------------- fused kNN: dist (f32) + register top-20 ----------------
// grid (256 ntiles, B). Block = 8 points, wave = 2 points.
// lane owns m = 256*t + 4*lane + i  (t=0..7, i=0..3) -> dv[t*4+i]
// NOTE: dv arrays must only be touched via static identities (rule #20) — the
// finalize lambda takes the array BY REFERENCE and is inlined per call site.
template <int C>
__global__ __launch_bounds__(256, 4) void fknn_k(const float* __restrict__ x, const float* __restrict__ xx,
                                                 int* __restrict__ idxout) {
  constexpr int CT = (C == 3) ? 4 : 8;
  constexpr int NCH = (C + CT - 1) / CT;   // 1 or 8
  constexpr int CP = CT * NCH;
  __shared__ float xxp[64 * 33];           // permuted norms: xxp[l*33 + t*4+i] = xx[256t+4l+i]
  __shared__ float xns[8][68];             // the 8 query points' features
  __shared__ float xtile[2][CT * 260];     // double-buffered m-tile, [c][m] rows padded
  const int tid = threadIdx.x, lane = tid & 63, wid = tid >> 6;
  const int b = blockIdx.y;
  const int n0 = blockIdx.x * 8;

  // stage permuted xx
#pragma unroll
  for (int k = 0; k < 8; ++k) {
    xxp[(tid >> 2) * 33 + k * 4 + (tid & 3)] = xx[b * 2048 + k * 256 + tid];
  }
  // stage query features (zero-padded channels)
  for (int q = tid; q < 8 * CP; q += 256) {
    const int c = q >> 3, p = q & 7;
    xns[p][c] = (c < C) ? x[((long long)b * C + c) * PTS + n0 + p] : 0.f;
  }

  auto stage = [&](int s, int buf) {
    const int mt = s & 7, ct = s >> 3;
#pragma unroll
    for (int kk = 0; kk < CT * 64; kk += 256) {
      const int idx4 = kk + tid;
      const int r = idx4 >> 6, c4 = (idx4 & 63) << 2;
      const int cg = ct * CT + r;
      float4 v = {0.f, 0.f, 0.f, 0.f};
      if (cg < C) v = *(const float4*)&x[((long long)b * C + cg) * PTS + mt * 256 + c4];
      *(float4*)&xtile[buf][r * 260 + c4] = v;
    }
  };

  float dv0[32] = {}, dv1[32] = {};
  const int p0 = wid * 2, p1 = p0 + 1;

  stage(0, 0);
  __syncthreads();
  int buf = 0;
  for (int ct = 0; ct < NCH; ++ct) {
    float xa[CT], xc[CT];
#pragma unroll
    for (int cj = 0; cj < CT; ++cj) {
      xa[cj] = xns[p0][ct * CT + cj];
      xc[cj] = xns[p1][ct * CT + cj];
    }
#pragma unroll
    for (int mt = 0; mt < 8; ++mt) {
      const int s = ct * 8 + mt;
      if (s + 1 < NCH * 8) stage(s + 1, buf ^ 1);
#pragma unroll
      for (int cj = 0; cj < CT; ++cj) {
        const f32x4 tv = *(const f32x4*)&xtile[buf][cj * 260 + lane * 4];
#pragma unroll
        for (int i = 0; i < 4; ++i) {
          dv0[mt * 4 + i] = fmaf(xa[cj], tv[i], dv0[mt * 4 + i]);
          dv1[mt * 4 + i] = fmaf(xc[cj], tv[i], dv1[mt * 4 + i]);
        }
      }
      buf ^= 1;
      __syncthreads();
    }
  }

  // finalize d = 2*inner - xx[m], select top-20 (exact, lowest-index ties) per point.
  // Array passed BY REFERENCE -> inlined with static register identity (no scratch).
  auto finalize = [&](float (&dv)[32], const int pidx) {
    float bv = -3.4e38f; int br = 0;
#pragma unroll
    for (int r = 0; r < 32; ++r) {
      dv[r] = 2.f * dv[r] - xxp[lane * 33 + r];
      if (dv[r] > bv) { bv = dv[r]; br = r; }   // ascending m within lane: keeps lowest
    }
    int bm = ((br >> 2) << 8) + (lane << 2) + (br & 3);
    int keep = 0;
    for (int rd = 0; rd < KK; ++rd) {
      float cv = bv; int cm = bm;
      argmax64(cv, cm);
      if (lane == rd) keep = cm;
      const int ol = (cm >> 2) & 63;               // owner lane
      const int orr = ((cm >> 8) << 2) | (cm & 3); // owner reg
      float nv = -3.4e38f; int nr = 0;
#pragma unroll
      for (int r = 0; r < 32; ++r) {
        if (lane == ol && r == orr) dv[r] = -3.4e38f;  // static index, predicated
        if (dv[r] > nv) { nv = dv[r]; nr = r; }
      }
      if (lane == ol) { bv = nv; bm = ((nr >> 2) << 8) + (lane << 2) + (nr & 3); }
    }
    if (lane < KK) idxout[((long long)b * PTS + pidx) * KK + lane] = keep;
  };
  finalize(dv0, n0 + p0);
  finalize(dv1, n0 + p1);
}

// ---------------- prep: combined PQ weights (f32) for edge2/edge3 ----------------
__global__ __launch_bounds__(256) void prep_k(
    const float* __restrict__ w3, const float* __restrict__ s3, const float* __restrict__ b3,
    const float* __restrict__ w5, const float* __restrict__ s5, const float* __restrict__ b5,
    float* __restrict__ wc3, float* __restrict__ sc3, float* __restrict__ bc3,
    float* __restrict__ wc5, float* __restrict__ sc5, float* __restrict__ bc5) {
  const int i = blockIdx.x * 256 + threadIdx.x;  // 16384
  const int half = i >> 13;
  const int r = i & 8191;
  const float* w = half ? w5 : w3;
  float* wcp = half ? wc5 : wc3;
  const int o = r >> 6, c = r & 63;
  wcp[r] = (o < 64) ? w[o * 128 + c] : (w[(o - 64) * 128 + 64 + c] - w[(o - 64) * 128 + c]);
  if (r < 128) {
    const float* s = half ? s5 : s3;
    const float* bb = half ? b5 : b3;
    float* scp = half ? sc5 : sc3;
    float* bcp = half ? bc5 : bc3;
    scp[r] = s[r & 63];
    bcp[r] = (r < 64) ? 0.f : bb[r - 64];
  }
}

// ---------------- split conv2 weights to bf16 hi/lo ----------------
__global__ __launch_bounds__(256) void wsplit_k(const float* __restrict__ w2, const float* __restrict__ w4,
                                                unsigned short* __restrict__ W2hi, unsigned short* __restrict__ W2lo,
                                                unsigned short* __restrict__ W4hi, unsigned short* __restrict__ W4lo) {
  const int i = blockIdx.x * 256 + threadIdx.x;  // 8192
  const float v = (i < 4096) ? w2[i] : w4[i - 4096];
  const unsigned short h = rne_bf16(v);
  const unsigned short l = rne_bf16(v - bf2f(h));
  if (i < 4096) { W2hi[i] = h; W2lo[i] = l; }
  else { W4hi[i - 4096] = h; W4lo[i - 4096] = l; }
}

// ---------------- PQ for edge1 (f32 out, [b][n][128]: P=0..63, Q=64..127) ----------------
__global__ __launch_bounds__(256) void pq1_k(const float* __restrict__ pts,
    const float* __restrict__ w1, const float* __restrict__ s1, const float* __restrict__ b1,
    float* __restrict__ PQ) {
  const int i = blockIdx.x * 256 + threadIdx.x;  // 16*2048*64
  const int o = i & 63;
  const int bn = i >> 6;
  const int b = bn >> 11, n = bn & 2047;
  const float* pb = pts + (long long)b * 3 * PTS;
  const float x = pb[n], y = pb[PTS + n], z = pb[2 * PTS + n];
  const float s = s1[o];
  const float wa0 = w1[o * 6], wa1 = w1[o * 6 + 1], wa2 = w1[o * 6 + 2];
  const float wb0 = w1[o * 6 + 3], wb1 = w1[o * 6 + 4], wb2 = w1[o * 6 + 5];
  PQ[(long long)bn * 128 + o] = s * (wa0 * x + wa1 * y + wa2 * z);
  PQ[(long long)bn * 128 + 64 + o] =
      fmaf(s, (wb0 - wa0) * x + (wb1 - wa1) * y + (wb2 - wa2) * z, b1[o]);
}

// ---------------- MFMA EdgeConv (split-bf16 3-pass): conv2 as pair-GEMM, max over k ----------------
static __device__ __forceinline__ void mkfrag2(const float4 p0, const float4 p1,
                                               const float4 q0, const float4 q1,
                                               bf8& hi, bf8& lo) {
  const float y[8] = {p0.x + q0.x, p0.y + q0.y, p0.z + q0.z, p0.w + q0.w,
                      p1.x + q1.x, p1.y + q1.y, p1.z + q1.z, p1.w + q1.w};
  union { unsigned u[4]; bf8 v; } rh, rlo;
#pragma unroll
  for (int i = 0; i < 4; ++i) {
    const float a = lrelu(y[2 * i]), b = lrelu(y[2 * i + 1]);
    const unsigned h = cvt2(a, b);
    rh.u[i] = h;
    rlo.u[i] = cvt2lo(a, b, h);
  }
  hi = rh.v; lo = rlo.v;
}

__global__ __launch_bounds__(256) void edgemf_k(
    const float* __restrict__ PQ, const int* __restrict__ idxb,
    const unsigned short* __restrict__ Whi, const unsigned short* __restrict__ Wlo,
    const float* __restrict__ s2v, const float* __restrict__ b2v,
    float* __restrict__ outC) {
  const int lane = threadIdx.x & 63, wid = threadIdx.x >> 6;
  const int g = blockIdx.x;                 // 16b * 256
  const int b = g >> 8;
  const int n0 = (g & 255) * 8 + wid * 2;   // 8 pts/block, 2 per wave
  bf8 wbh[4][2], wbl[4][2];
#pragma unroll
  for (int nf = 0; nf < 4; ++nf)
#pragma unroll
    for (int kt = 0; kt < 2; ++kt) {
      const int off = (16 * nf + (lane & 15)) * 64 + kt * 32 + (lane >> 4) * 8;
      wbh[nf][kt] = *(const bf8*)&Whi[off];
      wbl[nf][kt] = *(const bf8*)&Wlo[off];
    }
  const float* Pb = PQ + (long long)b * PTS * 128;
  f32x4 acc[4][4] = {};
  for (int pt = 0; pt < 2; ++pt) {
    const int n = n0 + pt;
    const int* ir = idxb + ((long long)b * PTS + n) * KK;
    const int co = (lane >> 4) * 8;
    const float4 q0a = *(const float4*)&Pb[n * 128 + 64 + co];
    const float4 q0b = *(const float4*)&Pb[n * 128 + 68 + co];
    const float4 q1a = *(const float4*)&Pb[n * 128 + 96 + co];
    const float4 q1b = *(const float4*)&Pb[n * 128 + 100 + co];
#pragma unroll
    for (int f = 0; f < 2; ++f) {
      const int j = f * 16 + (lane & 15);
      const int m = ir[j < KK ? j : 0];
      const float4 p0a = *(const float4*)&Pb[m * 128 + co];
      const float4 p0b = *(const float4*)&Pb[m * 128 + 4 + co];
      const float4 p1a = *(const float4*)&Pb[m * 128 + 32 + co];
      const float4 p1b = *(const float4*)&Pb[m * 128 + 36 + co];
      bf8 a0h, a0l, a1h, a1l;
      mkfrag2(p0a, p0b, q0a, q0b, a0h, a0l);
      mkfrag2(p1a, p1b, q1a, q1b, a1h, a1l);
      const int mf = pt * 2 + f;
#pragma unroll
      for (int nf = 0; nf < 4; ++nf) {
        acc[mf][nf] = __builtin_amdgcn_mfma_f32_16x16x32_bf16(a0h, wbh[nf][0], acc[mf][nf], 0, 0, 0);
        acc[mf][nf] = __builtin_amdgcn_mfma_f32_16x16x32_bf16(a0l, wbh[nf][0], acc[mf][nf], 0, 0, 0);
        acc[mf][nf] = __builtin_amdgcn_mfma_f32_16x16x32_bf16(a0h, wbl[nf][0], acc[mf][nf], 0, 0, 0);
      }
#pragma unroll
      for (int nf = 0; nf < 4; ++nf) {
        acc[mf][nf] = __builtin_amdgcn_mfma_f32_16x16x32_bf16(a1h, wbh[nf][1], acc[mf][nf], 0, 0, 0);
        acc[mf][nf] = __builtin_amdgcn_mfma_f32_16x16x32_bf16(a1l, wbh[nf][1], acc[mf][nf], 0, 0, 0);
        acc[mf][nf] = __builtin_amdgcn_mfma_f32_16x16x32_bf16(a1h, wbl[nf][1], acc[mf][nf], 0, 0, 0);
      }
    }
  }
#pragma unroll
  for (int nf = 0; nf < 4; ++nf) {
    const int o = 16 * nf + (lane & 15);
    const float so = s2v[o], bo = b2v[o];
#pragma unroll
    for (int pt = 0; pt < 2; ++pt) {
      float v = -3.4e38f;
#pragma unroll
      for (int f = 0; f < 2; ++f) {
        const int mf = pt * 2 + f;
#pragma unroll
        for (int r = 0; r < 4; ++r) v = fmaxf(v, lrelu(fmaf(so, acc[mf][nf][r], bo)));
      }
      v = fmaxf(v, __shfl_xor(v, 16, 64));
      v = fmaxf(v, __shfl_xor(v, 32, 64));
      if ((lane >> 4) == 0) outC[((long long)b * 64 + o) * PTS + n0 + pt] = v;
    }
  }
}

// ---------------- edge3: gather-max of lrelu(P+Q), f32 PQ ----------------
__global__ __launch_bounds__(256) void edge3f_k(const float* __restrict__ PQ,
                                                const int* __restrict__ idxb, float* __restrict__ outC) {
  const int lane = threadIdx.x & 63, wid = threadIdx.x >> 6;
  const int g = blockIdx.x;
  const int b = g >> 6, n0 = ((g & 63) << 5) + (wid << 3);
  const float* Pb = PQ + (long long)b * PTS * 128;
  for (int pt = 0; pt < 8; ++pt) {
    const int n = n0 + pt;
    const float qv = Pb[n * 128 + 64 + lane];
    const int* ir = idxb + ((long long)b * PTS + n) * KK;
    float gm = -3.4e38f;
#pragma unroll 4
    for (int j = 0; j < KK; ++j) {
      const int m = ir[j];
      gm = fmaxf(gm, lrelu(Pb[m * 128 + lane] + qv));
    }
    outC[((long long)b * 64 + lane) * PTS + n] = gm;
  }
}

// ---------------- bf16 MFMA GEMM, optional split-bf16 3-pass ----------------
// MODE 0: affine+lrelu -> [b][O][PTS] (+tadd) | MODE 1: affine+lrelu, max over n -> gpart
// MODE 2: affine+lrelu -> [b][PTS][O] f32     | MODE 3: affine only -> f32 [b][PTS][O]
struct SrcTab { const float* p[4]; long long bs[4]; };

template <int MODE, int SPLIT>
__global__ __launch_bounds__(256) void mfgemm_k(
    const float* __restrict__ W, int wstride, int c0, SrcTab tab, int C,
    const float* __restrict__ sv, const float* __restrict__ bv, const float* __restrict__ tadd,
    float* __restrict__ out, int O) {
  __shared__ __align__(16) short Wl[(1 + SPLIT) * 128 * 32];
  __shared__ __align__(16) short Xl[(1 + SPLIT) * 128 * 32];
  __shared__ float red[2][128];
  const int tid = threadIdx.x, lane = tid & 63, wid = tid >> 6;
  const int nt = blockIdx.x, ot = blockIdx.y, b = blockIdx.z;
  const int n0 = nt * 128, o0 = ot * 128;
  const int wm = wid >> 1, wn = wid & 1;
  f32x4 acc[4][4] = {};
  for (int cc = 0; cc < C; cc += 32) {
    __syncthreads();
    {
      const int o = tid >> 1, hf = tid & 1;
      const float* src = &W[(long long)(o0 + o) * wstride + c0 + cc + hf * 16];
      const float4 v0 = *(const float4*)src;
      const float4 v1 = *(const float4*)(src + 4);
      const float4 v2 = *(const float4*)(src + 8);
      const float4 v3 = *(const float4*)(src + 12);
      uint4 d0, d1;
      d0.x = cvt2(v0.x, v0.y); d0.y = cvt2(v0.z, v0.w);
      d0.z = cvt2(v1.x, v1.y); d0.w = cvt2(v1.z, v1.w);
      d1.x = cvt2(v2.x, v2.y); d1.y = cvt2(v2.z, v2.w);
      d1.z = cvt2(v3.x, v3.y); d1.w = cvt2(v3.z, v3.w);
      *(uint4*)&Wl[o * 32 + swz(o, hf * 2) * 8] = d0;
      *(uint4*)&Wl[o * 32 + swz(o, hf * 2 + 1) * 8] = d1;
      if (SPLIT) {
        uint4 e0, e1;
        e0.x = cvt2lo(v0.x, v0.y, d0.x); e0.y = cvt2lo(v0.z, v0.w, d0.y);
        e0.z = cvt2lo(v1.x, v1.y, d0.z); e0.w = cvt2lo(v1.z, v1.w, d0.w);
        e1.x = cvt2lo(v2.x, v2.y, d1.x); e1.y = cvt2lo(v2.z, v2.w, d1.y);
        e1.z = cvt2lo(v3.x, v3.y, d1.z); e1.w = cvt2lo(v3.z, v3.w, d1.w);
        *(uint4*)&Wl[4096 + o * 32 + swz(o, hf * 2) * 8] = e0;
        *(uint4*)&Wl[4096 + o * 32 + swz(o, hf * 2 + 1) * 8] = e1;
      }
    }
    {
      const int n = tid & 127, ch = (tid >> 7) * 16;
      float val[16];
#pragma unroll
      for (int i = 0; i < 16; ++i) {
        const int cg = cc + ch + i;
        val[i] = tab.p[cg >> 6][tab.bs[cg >> 6] * b + (long long)(cg & 63) * PTS + n0 + n];
      }
      uint4 d0, d1;
      d0.x = cvt2(val[0], val[1]);   d0.y = cvt2(val[2], val[3]);
      d0.z = cvt2(val[4], val[5]);   d0.w = cvt2(val[6], val[7]);
      d1.x = cvt2(val[8], val[9]);   d1.y = cvt2(val[10], val[11]);
      d1.z = cvt2(val[12], val[13]); d1.w = cvt2(val[14], val[15]);
      const int s0 = ch >> 3;
      *(uint4*)&Xl[n * 32 + swz(n, s0) * 8] = d0;
      *(uint4*)&Xl[n * 32 + swz(n, s0 + 1) * 8] = d1;
      if (SPLIT) {
        uint4 e0, e1;
        e0.x = cvt2lo(val[0], val[1], d0.x);   e0.y = cvt2lo(val[2], val[3], d0.y);
        e0.z = cvt2lo(val[4], val[5], d0.z);   e0.w = cvt2lo(val[6], val[7], d0.w);
        e1.x = cvt2lo(val[8], val[9], d1.x);   e1.y = cvt2lo(val[10], val[11], d1.y);
        e1.z = cvt2lo(val[12], val[13], d1.z); e1.w = cvt2lo(val[14], val[15], d1.w);
        *(uint4*)&Xl[4096 + n * 32 + swz(n, s0) * 8] = e0;
        *(uint4*)&Xl[4096 + n * 32 + swz(n, s0 + 1) * 8] = e1;
      }
    }
    __syncthreads();
    bf8 afh[4], bfh[4], afl[4], bfl[4];
#pragma unroll
    for (int mf = 0; mf < 4; ++mf) {
      const int arow = wm * 64 + mf * 16 + (lane & 15);
      const int aoff = arow * 32 + swz(arow, lane >> 4) * 8;
      afh[mf] = *(const bf8*)&Wl[aoff];
      if (SPLIT) afl[mf] = *(const bf8*)&Wl[4096 + aoff];
    }
#pragma unroll
    for (int nf = 0; nf < 4; ++nf) {
      const int brow = wn * 64 + nf * 16 + (lane & 15);
      const int boff = brow * 32 + swz(brow, lane >> 4) * 8;
      bfh[nf] = *(const bf8*)&Xl[boff];
      if (SPLIT) bfl[nf] = *(const bf8*)&Xl[4096 + boff];
    }
#pragma unroll
    for (int mf = 0; mf < 4; ++mf)
#pragma unroll
      for (int nf = 0; nf < 4; ++nf) {
        acc[mf][nf] = __builtin_amdgcn_mfma_f32_16x16x32_bf16(afh[mf], bfh[nf], acc[mf][nf], 0, 0, 0);
        if (SPLIT) {
          acc[mf][nf] = __builtin_amdgcn_mfma_f32_16x16x32_bf16(afl[mf], bfh[nf], acc[mf][nf], 0, 0, 0);
          acc[mf][nf] = __builtin_amdgcn_mfma_f32_16x16x32_bf16(afh[mf], bfl[nf], acc[mf][nf], 0, 0, 0);
        }
      }
  }
  if (MODE == 1) {
#pragma unroll
    for (int mf = 0; mf < 4; ++mf)
#pragma unroll
      for (int r = 0; r < 4; ++r) {
        const int orl = wm * 64 + mf * 16 + (lane >> 4) * 4 + r;
        const int o = o0 + orl;
        const float s = sv[o], bb = bv[o];
        float v = -3.4e38f;
#pragma unroll
        for (int nf = 0; nf < 4; ++nf) v = fmaxf(v, lrelu(fmaf(s, acc[mf][nf][r], bb)));
        v = fmaxf(v, __shfl_xor(v, 1, 64));
        v = fmaxf(v, __shfl_xor(v, 2, 64));
        v = fmaxf(v, __shfl_xor(v, 4, 64));
        v = fmaxf(v, __shfl_xor(v, 8, 64));
        if ((lane & 15) == 0) red[wn][orl] = v;
      }
    __syncthreads();
    if (tid < 128) {
      const float m = fmaxf(red[0][tid], red[1][tid]);
      out[((long long)b * 16 + nt) * 1024 + o0 + tid] = m;
    }
  } else if (MODE == 0) {
#pragma unroll
    for (int mf = 0; mf < 4; ++mf)
#pragma unroll
      for (int r = 0; r < 4; ++r) {
        const int o = o0 + wm * 64 + mf * 16 + (lane >> 4) * 4 + r;
        const float s = sv[o], bb = bv[o];
        const float tv = (tadd != nullptr) ? tadd[(long long)b * O + o] : 0.f;
        float* op = out + ((long long)b * O + o) * PTS + n0 + wn * 64 + (lane & 15);
#pragma unroll
        for (int nf = 0; nf < 4; ++nf)
          op[nf * 16] = lrelu(fmaf(s, acc[mf][nf][r] + tv, bb));
      }
  } else if (MODE == 2) {
#pragma unroll
    for (int mf = 0; mf < 4; ++mf) {
      const int ob = wm * 64 + mf * 16 + (lane >> 4) * 4;
      float s4[4], b4[4];
#pragma unroll
      for (int r = 0; r < 4; ++r) { s4[r] = sv[o0 + ob + r]; b4[r] = bv[o0 + ob + r]; }
#pragma unroll
      for (int nf = 0; nf < 4; ++nf) {
        const int n = n0 + wn * 64 + nf * 16 + (lane & 15);
        float4 v;
        v.x = lrelu(fmaf(s4[0], acc[mf][nf][0], b4[0]));
        v.y = lrelu(fmaf(s4[1], acc[mf][nf][1], b4[1]));
        v.z = lrelu(fmaf(s4[2], acc[mf][nf][2], b4[2]));
        v.w = lrelu(fmaf(s4[3], acc[mf][nf][3], b4[3]));
        *(float4*)&out[((long long)b * PTS + n) * O + o0 + ob] = v;
      }
    }
  } else {  // MODE 3: affine only, f32 [b][PTS][O]
#pragma unroll
    for (int mf = 0; mf < 4; ++mf) {
      const int ob = wm * 64 + mf * 16 + (lane >> 4) * 4;
      float s4[4], b4[4];
#pragma unroll
      for (int r = 0; r < 4; ++r) { s4[r] = sv[o0 + ob + r]; b4[r] = bv[o0 + ob + r]; }
#pragma unroll
      for (int nf = 0; nf < 4; ++nf) {
        const int n = n0 + wn * 64 + nf * 16 + (lane & 15);
        float4 v;
        v.x = fmaf(s4[0], acc[mf][nf][0], b4[0]);
        v.y = fmaf(s4[1], acc[mf][nf][1], b4[1]);
        v.z = fmaf(s4[2], acc[mf][nf][2], b4[2]);
        v.w = fmaf(s4[3], acc[mf][nf][3], b4[3]);
        *(float4*)&out[((long long)b * PTS + n) * O + o0 + ob] = v;
      }
    }
  }
}

// ---------------- tvec (f32 exact; gfin folded: reads gpart) ----------------
__global__ __launch_bounds__(256) void tvec_k(
    const float* __restrict__ cls, const float* __restrict__ wc, const float* __restrict__ sc,
    const float* __restrict__ bc, const float* __restrict__ gp, const float* __restrict__ wf1,
    float* __restrict__ tvec) {
  __shared__ float gs[1024];
  __shared__ float cvs[64];
  const int b = blockIdx.x, tid = threadIdx.x;
  for (int q = tid; q < 1024; q += 256) {
    float m = -3.4e38f;
#pragma unroll 4
    for (int t = 0; t < 16; ++t) m = fmaxf(m, gp[((long long)b * 16 + t) * 1024 + q]);
    gs[q] = m;
  }
  if (tid < 64) {
    float a = 0.f;
#pragma unroll
    for (int j = 0; j < 16; ++j) a = fmaf(wc[tid * 16 + j], cls[b * 16 + j], a);
    cvs[tid] = lrelu(fmaf(sc[tid], a, bc[tid]));
  }
  __syncthreads();
  const float* wr = wf1 + (long long)tid * 1280;
  float a0 = 0.f, a1 = 0.f;
  for (int c = 0; c < 1024; c += 4) {
    const float4 w = *(const float4*)&wr[c];
    const float4 gv = *(const float4*)&gs[c];
    a0 = fmaf(w.x, gv.x, a0); a1 = fmaf(w.y, gv.y, a1);
    a0 = fmaf(w.z, gv.z, a0); a1 = fmaf(w.w, gv.w, a1);
  }
#pragma unroll
  for (int c = 0; c < 64; c += 4) {
    const float4 w = *(const float4*)&wr[1024 + c];
    const float4 cv = *(const float4*)&cvs[c];
    a0 = fmaf(w.x, cv.x, a0); a1 = fmaf(w.y, cv.y, a1);
    a0 = fmaf(w.z, cv.z, a0); a1 = fmaf(w.w, cv.w, a1);
  }
  tvec[b * 256 + tid] = a0 + a1;
}

// ---------------- logits + log_softmax ----------------
__global__ __launch_bounds__(256) void logits_k(const float* __restrict__ f3t, const float* __restrict__ wf4,
                                                float* __restrict__ out) {
  __shared__ float wT[6464];
  const int tid = threadIdx.x, lane = tid & 63, wv = tid >> 6;
  for (int q = tid; q < 6400; q += 256) {
    const int o = q >> 7, c = q & 127;
    wT[c * 50 + o] = wf4[q];
  }
  __syncthreads();
  const long long pn = (long long)blockIdx.x * 4 + wv;
  const float lo = f3t[pn * 128 + lane], hi = f3t[pn * 128 + 64 + lane];
  float a0 = 0.f, a1 = 0.f;
#pragma unroll
  for (int c = 0; c < 64; c += 2) {
    a0 = fmaf(wT[c * 50 + lane], rl(lo, c), a0);
    a1 = fmaf(wT[(c + 1) * 50 + lane], rl(lo, c + 1), a1);
  }
#pragma unroll
  for (int c = 0; c < 64; c += 2) {
    a0 = fmaf(wT[(64 + c) * 50 + lane], rl(hi, c), a0);
    a1 = fmaf(wT[(65 + c) * 50 + lane], rl(hi, c + 1), a1);
  }
  const float logit = (lane < 50) ? (a0 + a1) : -3.4e38f;
  float M = logit;
#pragma unroll
  for (int mask = 1; mask < 64; mask <<= 1) M = fmaxf(M, __shfl_xor(M, mask, 64));
  const float ex = (lane < 50) ? __expf(logit - M) : 0.f;
  float S = ex;
#pragma unroll
  for (int mask = 1; mask < 64; mask <<= 1) S += __shfl_xor(S, mask, 64);
  if (lane < 50) out[pn * 50 + lane] = logit - M - __logf(S);
}

extern "C" void kernel_launch(void* const* d_in, const int* in_sizes, int n_in,
                              void* d_out, int out_size, void* d_ws, size_t ws_size,
                              hipStream_t stream) {
  (void)in_sizes; (void)n_in; (void)out_size; (void)ws_size;
  const float* points = (const float*)d_in[0];
  const float* cls = (const float*)d_in[1];
  const float* w1 = (const float*)d_in[2];
  const float* s1 = (const float*)d_in[3];
  const float* b1 = (const float*)d_in[4];
  const float* w2 = (const float*)d_in[5];
  const float* s2 = (const float*)d_in[6];
  const float* b2 = (const float*)d_in[7];
  const float* w3 = (const float*)d_in[8];
  const float* s3 = (const float*)d_in[9];
  const float* b3 = (const float*)d_in[10];
  const float* w4 = (const float*)d_in[11];
  const float* s4 = (const float*)d_in[12];
  const float* b4 = (const float*)d_in[13];
  const float* w5 = (const float*)d_in[14];
  const float* s5 = (const float*)d_in[15];
  const float* b5 = (const float*)d_in[16];
  const float* w6 = (const float*)d_in[17];
  const float* s6 = (const float*)d_in[18];
  const float* b6 = (const float*)d_in[19];
  const float* wc = (const float*)d_in[20];
  const float* sc = (const float*)d_in[21];
  const float* bc = (const float*)d_in[22];
  const float* wf1 = (const float*)d_in[23];
  const float* sf1 = (const float*)d_in[24];
  const float* bf1 = (const float*)d_in[25];
  const float* wf2 = (const float*)d_in[26];
  const float* sf2 = (const float*)d_in[27];
  const float* bf2 = (const float*)d_in[28];
  const float* wf3 = (const float*)d_in[29];
  const float* sf3 = (const float*)d_in[30];
  const float* bf3 = (const float*)d_in[31];
  const float* wf4 = (const float*)d_in[32];
  float* out = (float*)d_out;
  float* ws = (float*)d_ws;

  // workspace (floats): x1c@0  x2c@2097152  x3c@4194304  f1c@8388608(..16777216)
  // PQf/f3t time-share f1c region; f2c aliases x*c (dead by then); aux @16777216+
  float* x1c = ws;
  float* x2c = ws + 2097152LL;
  float* x3c = ws + 4194304LL;
  float* f1c = ws + 8388608LL;
  float* f2c = ws;
  float* f3t = ws + 8388608LL;
  float* PQf = ws + 8388608LL;
  int* idx = (int*)(ws + 16777216LL);
  float* xxb = ws + 17432576LL;
  float* gpart = ws + 17465344LL;
  float* tvec = ws + 17743872LL;
  float* wc3 = ws + 17747968LL;
  float* sc3 = ws + 17756160LL;
  float* bc3 = ws + 17756288LL;
  float* wc5 = ws + 17756416LL;
  float* sc5 = ws + 17764608LL;
  float* bc5 = ws + 17764736LL;
  unsigned short* W2hi = (unsigned short*)(ws + 17764864LL);
  unsigned short* W2lo = (unsigned short*)(ws + 17766912LL);
  unsigned short* W4hi = (unsigned short*)(ws + 17768960LL);
  unsigned short* W4lo = (unsigned short*)(ws + 17771008LL);

  SrcTab tabX{{x1c, x2c, x3c, nullptr}, {64LL * PTS, 64LL * PTS, 64LL * PTS, 0}};
  SrcTab tabX1{{x1c, nullptr, nullptr, nullptr}, {64LL * PTS, 0, 0, 0}};
  SrcTab tabX2{{x2c, nullptr, nullptr, nullptr}, {64LL * PTS, 0, 0, 0}};
  SrcTab tabF1{{f1c, f1c + 64 * PTS, f1c + 128 * PTS, f1c + 192 * PTS},
               {256LL * PTS, 256LL * PTS, 256LL * PTS, 256LL * PTS}};
  SrcTab tabF2{{f2c, f2c + 64 * PTS, f2c + 128 * PTS, f2c + 192 * PTS},
               {256LL * PTS, 256LL * PTS, 256LL * PTS, 256LL * PTS}};

  prep_k<<<64, 256, 0, stream>>>(w3, s3, b3, w5, s5, b5, wc3, sc3, bc3, wc5, sc5, bc5);
  wsplit_k<<<32, 256, 0, stream>>>(w2, w4, W2hi, W2lo, W4hi, W4lo);

  // ---- kNN 1 (fused, f32-exact) + edge1 (split-MFMA) ----
  xnorm_k<3><<<128, 256, 0, stream>>>(points, xxb);
  fknn_k<3><<<dim3(256, 16), 256, 0, stream>>>(points, xxb, idx);
  pq1_k<<<8192, 256, 0, stream>>>(points, w1, s1, b1, PQf);
  edgemf_k<<<4096, 256, 0, stream>>>(PQf, idx, W2hi, W2lo, s2, b2, x1c);

  // ---- kNN 2 + edge2 (split-MFMA) ----
  xnorm_k<64><<<128, 256, 0, stream>>>(x1c, xxb);
  fknn_k<64><<<dim3(256, 16), 256, 0, stream>>>(x1c, xxb, idx);
  mfgemm_k<3, 1><<<dim3(16, 1, 16), 256, 0, stream>>>(wc3, 64, 0, tabX1, 64, sc3, bc3, nullptr, PQf, 128);
  edgemf_k<<<4096, 256, 0, stream>>>(PQf, idx, W4hi, W4lo, s4, b4, x2c);

  // ---- kNN 3 + edge3 ----
  xnorm_k<64><<<128, 256, 0, stream>>>(x2c, xxb);
  fknn_k<64><<<dim3(256, 16), 256, 0, stream>>>(x2c, xxb, idx);
  mfgemm_k<3, 1><<<dim3(16, 1, 16), 256, 0, stream>>>(wc5, 64, 0, tabX2, 64, sc5, bc5, nullptr, PQf, 128);
  edge3f_k<<<1024, 256, 0, stream>>>(PQf, idx, x3c);

  // ---- head (split-MFMA) ----
  mfgemm_k<1, 1><<<dim3(16, 8, 16), 256, 0, stream>>>(w6, 192, 0, tabX, 192, s6, b6, nullptr, gpart, 1024);
  tvec_k<<<16, 256, 0, stream>>>(cls, wc, sc, bc, gpart, wf1, tvec);
  mfgemm_k<0, 1><<<dim3(16, 2, 16), 256, 0, stream>>>(wf1, 1280, 1088, tabX, 192, sf1, bf1, tvec, f1c, 256);
  mfgemm_k<0, 1><<<dim3(16, 2, 16), 256, 0, stream>>>(wf2, 256, 0, tabF1, 256, sf2, bf2, nullptr, f2c, 256);
  mfgemm_k<2, 1><<<dim3(16, 1, 16), 256, 0, stream>>>(wf3, 256, 0, tabF2, 256, sf3, bf3, nullptr, f3t, 128);
  logits_k<<<8192, 256, 0, stream>>>(f3t, wf4, out);
}

// Round 8
// 1570.349 us; speedup vs baseline: 4.0753x; 4.0753x over previous
//
#include <hip/hip_runtime.h>

constexpr int PTS = 2048;   // points per batch
constexpr int KK  = 20;     // knn

typedef __attribute__((ext_vector_type(8))) short bf8;
typedef __attribute__((ext_vector_type(4))) float f32x4;

static __device__ __forceinline__ float lrelu(float x) { return fmaxf(x, 0.2f * x); }
static __device__ __forceinline__ float rl(float v, int l) {
  return __int_as_float(__builtin_amdgcn_readlane(__float_as_int(v), l));
}
static __device__ __forceinline__ unsigned cvt2(float lo, float hi) {
  unsigned r;
  asm("v_cvt_pk_bf16_f32 %0, %1, %2" : "=v"(r) : "v"(lo), "v"(hi));
  return r;
}
// residual after bf16-hi extraction: packs bf16(a - hi(a)), bf16(b - hi(b))
static __device__ __forceinline__ unsigned cvt2lo(float a, float b, unsigned h) {
  return cvt2(a - __uint_as_float(h << 16), b - __uint_as_float(h & 0xffff0000u));
}
static __device__ __forceinline__ unsigned short rne_bf16(float v) {
  unsigned u = __float_as_uint(v);
  return (unsigned short)((u + 0x7fffu + ((u >> 16) & 1u)) >> 16);
}
static __device__ __forceinline__ float bf2f(unsigned short u) {
  return __uint_as_float(((unsigned)u) << 16);
}
static __device__ __forceinline__ int swz(int row, int slot) {
  return slot ^ (row & 3) ^ ((row >> 2) & 3);   // 16B-slot swizzle, conflict-free
}
static __device__ __forceinline__ void argmax64(float& v, int& m) {
#pragma unroll
  for (int mask = 1; mask < 64; mask <<= 1) {
    float ov = __shfl_xor(v, mask, 64);
    int om = __shfl_xor(m, mask, 64);
    if (ov > v || (ov == v && om < m)) { v = ov; m = om; }
  }
}

// ---------------- xx[b][m] = sum_c x[c][m]^2 ----------------
template <int C>
__global__ __launch_bounds__(256) void xnorm_k(const float* __restrict__ x, float* __restrict__ xx) {
  const int i = blockIdx.x * 256 + threadIdx.x;
  const int b = i >> 11, m = i & 2047;
  float s = 0.f;
#pragma unroll
  for (int c = 0; c < C; ++c) {
    const float v = x[((long long)b * C + c) * PTS + m];
    s = fmaf(v, v, s);
  }
  xx[i] = s;
}

// ---------------- dist GEMM (f32, topology-critical): D[bl][n][m] = 2*<x_n,x_m> - xx[m] ----------------
template <int C>
__global__ __launch_bounds__(256) void dist_k(const float* __restrict__ x, const float* __restrict__ xx,
                                              float* __restrict__ D, int bo) {
  constexpr int CP = (C == 3) ? 4 : 32;
  __shared__ float xn[CP * 132];
  __shared__ float xm[CP * 132];
  const int tid = threadIdx.x;
  const int mt = blockIdx.x, nt = blockIdx.y, bl = blockIdx.z;
  const int b = bo + bl;
  const int n0 = nt * 128, m0 = mt * 128;
  const int og = tid & 15, ng = tid >> 4;
  float acc[8][8] = {};
  for (int cc = 0; cc < C; cc += CP) {
    __syncthreads();
    for (int q = tid; q < CP * 32; q += 256) {
      const int c = q >> 5, n4 = (q & 31) << 2;
      float4 vn = {0.f, 0.f, 0.f, 0.f}, vm = {0.f, 0.f, 0.f, 0.f};
      if (cc + c < C) {
        vn = *(const float4*)&x[((long long)b * C + cc + c) * PTS + n0 + n4];
        vm = *(const float4*)&x[((long long)b * C + cc + c) * PTS + m0 + n4];
      }
      *(float4*)&xn[c * 132 + n4] = vn;
      *(float4*)&xm[c * 132 + n4] = vm;
    }
    __syncthreads();
#pragma unroll
    for (int c = 0; c < CP; ++c) {
      const float4 a0 = *(const float4*)&xn[c * 132 + ng * 8];
      const float4 a1 = *(const float4*)&xn[c * 132 + ng * 8 + 4];
      const float4 b0 = *(const float4*)&xm[c * 132 + og * 8];
      const float4 b1 = *(const float4*)&xm[c * 132 + og * 8 + 4];
      const float na[8] = {a0.x, a0.y, a0.z, a0.w, a1.x, a1.y, a1.z, a1.w};
      const float ma[8] = {b0.x, b0.y, b0.z, b0.w, b1.x, b1.y, b1.z, b1.w};
#pragma unroll
      for (int i = 0; i < 8; ++i)
#pragma unroll
        for (int j = 0; j < 8; ++j) acc[i][j] = fmaf(na[i], ma[j], acc[i][j]);
    }
  }
  const float4 xx0 = *(const float4*)&xx[(long long)b * PTS + m0 + og * 8];
  const float4 xx1 = *(const float4*)&xx[(long long)b * PTS + m0 + og * 8 + 4];
  const float xa[8] = {xx0.x, xx0.y, xx0.z, xx0.w, xx1.x, xx1.y, xx1.z, xx1.w};
#pragma unroll
  for (int i = 0; i < 8; ++i) {
    float r[8];
#pragma unroll
    for (int j = 0; j < 8; ++j) r[j] = 2.f * acc[i][j] - xa[j];
    float* op = D + ((long long)bl * PTS + n0 + ng * 8 + i) * PTS + m0 + og * 8;
    float4 v0 = {r[0], r[1], r[2], r[3]};
    float4 v1 = {r[4], r[5], r[6], r[7]};
    *(float4*)op = v0;
    *(float4*)(op + 4) = v1;
  }
}

// ---------------- top-20 selection: 1 wave per point, 4 points/block ----------------
__global__ __launch_bounds__(256) void select_k(const float* __restrict__ D, int* __restrict__ idxout, int bo) {
  __shared__ float sh[4 * 2112];
  const int tid = threadIdx.x, lane = tid & 63, wid = tid >> 6;
  const long long pn = (long long)blockIdx.x * 4 + wid;
  const int bl = (int)(pn >> 11);
  const int n = (int)(pn & 2047);
  const int b = bo + bl;
  float* dp = sh + wid * 2112;
  const float* row = D + pn * PTS;
#pragma unroll
  for (int q = 0; q < 8; ++q) {
    const int m = q * 256 + lane * 4;
    const float4 v = *(const float4*)&row[m];
    dp[((m + 0) & 63) * 33 + ((m + 0) >> 6)] = v.x;
    dp[((m + 1) & 63) * 33 + ((m + 1) >> 6)] = v.y;
    dp[((m + 2) & 63) * 33 + ((m + 2) >> 6)] = v.z;
    dp[((m + 3) & 63) * 33 + ((m + 3) >> 6)] = v.w;
  }
  asm volatile("s_waitcnt lgkmcnt(0)" ::: "memory");
  float bv = -3.4e38f; int bm = 1 << 29;
#pragma unroll 4
  for (int j = 0; j < 32; ++j) {
    float v = dp[lane * 33 + j];
    if (v > bv) { bv = v; bm = lane + (j << 6); }  // ascending m: strict > keeps lowest idx
  }
  int keep = 0;
  for (int r = 0; r < KK; ++r) {
    float cv = bv; int cm = bm;
    argmax64(cv, cm);
    if (lane == r) keep = cm;
    const int sm = cm & 63;
    if (lane == 0) dp[sm * 33 + (cm >> 6)] = -3.4e38f;  // persistent invalidation
    asm volatile("s_waitcnt lgkmcnt(0)" ::: "memory");
    const int jj = lane & 31;  // all-lane rescan of seg sm
    float v2 = dp[sm * 33 + jj];
    int m2 = sm + (jj << 6);
    if (m2 == cm) v2 = -3.4e38f;
    argmax64(v2, m2);
    if (lane == sm) { bv = v2; bm = m2; }
  }
  if (lane < KK) idxout[((long long)b * PTS + n) * KK + lane] = keep;
}

// ---------------- prep: combined PQ weights (f32) for edge2/edge3 ----------------
__global__ __launch_bounds__(256) void prep_k(
    const float* __restrict__ w3, const float* __restrict__ s3, const float* __restrict__ b3,
    const float* __restrict__ w5, const float* __restrict__ s5, const float* __restrict__ b5,
    float* __restrict__ wc3, float* __restrict__ sc3, float* __restrict__ bc3,
    float* __restrict__ wc5, float* __restrict__ sc5, float* __restrict__ bc5) {
  const int i = blockIdx.x * 256 + threadIdx.x;  // 16384
  const int half = i >> 13;
  const int r = i & 8191;
  const float* w = half ? w5 : w3;
  float* wcp = half ? wc5 : wc3;
  const int o = r >> 6, c = r & 63;
  wcp[r] = (o < 64) ? w[o * 128 + c] : (w[(o - 64) * 128 + 64 + c] - w[(o - 64) * 128 + c]);
  if (r < 128) {
    const float* s = half ? s5 : s3;
    const float* bb = half ? b5 : b3;
    float* scp = half ? sc5 : sc3;
    float* bcp = half ? bc5 : bc3;
    scp[r] = s[r & 63];
    bcp[r] = (r < 64) ? 0.f : bb[r - 64];
  }
}

// ---------------- split conv2 weights to bf16 hi/lo ----------------
__global__ __launch_bounds__(256) void wsplit_k(const float* __restrict__ w2, const float* __restrict__ w4,
                                                unsigned short* __restrict__ W2hi, unsigned short* __restrict__ W2lo,
                                                unsigned short* __restrict__ W4hi, unsigned short* __restrict__ W4lo) {
  const int i = blockIdx.x * 256 + threadIdx.x;  // 8192
  const float v = (i < 4096) ? w2[i] : w4[i - 4096];
  const unsigned short h = rne_bf16(v);
  const unsigned short l = rne_bf16(v - bf2f(h));
  if (i < 4096) { W2hi[i] = h; W2lo[i] = l; }
  else { W4hi[i - 4096] = h; W4lo[i - 4096] = l; }
}

// ---------------- PQ for edge1 (f32 out, [b][n][128]: P=0..63, Q=64..127) ----------------
__global__ __launch_bounds__(256) void pq1_k(const float* __restrict__ pts,
    const float* __restrict__ w1, const float* __restrict__ s1, const float* __restrict__ b1,
    float* __restrict__ PQ) {
  const int i = blockIdx.x * 256 + threadIdx.x;  // 16*2048*64
  const int o = i & 63;
  const int bn = i >> 6;
  const int b = bn >> 11, n = bn & 2047;
  const float* pb = pts + (long long)b * 3 * PTS;
  const float x = pb[n], y = pb[PTS + n], z = pb[2 * PTS + n];
  const float s = s1[o];
  const float wa0 = w1[o * 6], wa1 = w1[o * 6 + 1], wa2 = w1[o * 6 + 2];
  const float wb0 = w1[o * 6 + 3], wb1 = w1[o * 6 + 4], wb2 = w1[o * 6 + 5];
  PQ[(long long)bn * 128 + o] = s * (wa0 * x + wa1 * y + wa2 * z);
  PQ[(long long)bn * 128 + 64 + o] =
      fmaf(s, (wb0 - wa0) * x + (wb1 - wa1) * y + (wb2 - wa2) * z, b1[o]);
}

// ---------------- MFMA EdgeConv (split-bf16 3-pass): conv2 as pair-GEMM, max over k ----------------
static __device__ __forceinline__ void mkfrag2(const float4 p0, const float4 p1,
                                               const float4 q0, const float4 q1,
                                               bf8& hi, bf8& lo) {
  const float y[8] = {p0.x + q0.x, p0.y + q0.y, p0.z + q0.z, p0.w + q0.w,
                      p1.x + q1.x, p1.y + q1.y, p1.z + q1.z, p1.w + q1.w};
  union { unsigned u[4]; bf8 v; } rh, rlo;
#pragma unroll
  for (int i = 0; i < 4; ++i) {
    const float a = lrelu(y[2 * i]), b = lrelu(y[2 * i + 1]);
    const unsigned h = cvt2(a, b);
    rh.u[i] = h;
    rlo.u[i] = cvt2lo(a, b, h);
  }
  hi = rh.v; lo = rlo.v;
}

__global__ __launch_bounds__(256) void edgemf_k(
    const float* __restrict__ PQ, const int* __restrict__ idxb,
    const unsigned short* __restrict__ Whi, const unsigned short* __restrict__ Wlo,
    const float* __restrict__ s2v, const float* __restrict__ b2v,
    float* __restrict__ outC) {
  const int lane = threadIdx.x & 63, wid = threadIdx.x >> 6;
  const int g = blockIdx.x;                 // 16b * 256
  const int b = g >> 8;
  const int n0 = (g & 255) * 8 + wid * 2;   // 8 pts/block, 2 per wave
  bf8 wbh[4][2], wbl[4][2];
#pragma unroll
  for (int nf = 0; nf < 4; ++nf)
#pragma unroll
    for (int kt = 0; kt < 2; ++kt) {
      const int off = (16 * nf + (lane & 15)) * 64 + kt * 32 + (lane >> 4) * 8;
      wbh[nf][kt] = *(const bf8*)&Whi[off];
      wbl[nf][kt] = *(const bf8*)&Wlo[off];
    }
  const float* Pb = PQ + (long long)b * PTS * 128;
  const int co = (lane >> 4) * 8;
  // hoist neighbor indices + Q fragments for BOTH points (breaks idx->gather dependency chain)
  int mm[2][2];
  float4 qa[2][2], qb[2][2];
#pragma unroll
  for (int pt = 0; pt < 2; ++pt) {
    const int n = n0 + pt;
    const int* ir = idxb + ((long long)b * PTS + n) * KK;
    const int j1 = 16 + (lane & 15);
    mm[pt][0] = ir[lane & 15];
    mm[pt][1] = ir[j1 < KK ? j1 : 0];
    qa[pt][0] = *(const float4*)&Pb[n * 128 + 64 + co];
    qb[pt][0] = *(const float4*)&Pb[n * 128 + 68 + co];
    qa[pt][1] = *(const float4*)&Pb[n * 128 + 96 + co];
    qb[pt][1] = *(const float4*)&Pb[n * 128 + 100 + co];
  }
  f32x4 acc[4][4] = {};
#pragma unroll
  for (int pt = 0; pt < 2; ++pt) {
#pragma unroll
    for (int f = 0; f < 2; ++f) {
      const int m = mm[pt][f];
      const float4 p0a = *(const float4*)&Pb[m * 128 + co];
      const float4 p0b = *(const float4*)&Pb[m * 128 + 4 + co];
      const float4 p1a = *(const float4*)&Pb[m * 128 + 32 + co];
      const float4 p1b = *(const float4*)&Pb[m * 128 + 36 + co];
      bf8 a0h, a0l, a1h, a1l;
      mkfrag2(p0a, p0b, qa[pt][0], qb[pt][0], a0h, a0l);
      mkfrag2(p1a, p1b, qa[pt][1], qb[pt][1], a1h, a1l);
      const int mf = pt * 2 + f;
#pragma unroll
      for (int nf = 0; nf < 4; ++nf) {
        acc[mf][nf] = __builtin_amdgcn_mfma_f32_16x16x32_bf16(a0h, wbh[nf][0], acc[mf][nf], 0, 0, 0);
        acc[mf][nf] = __builtin_amdgcn_mfma_f32_16x16x32_bf16(a0l, wbh[nf][0], acc[mf][nf], 0, 0, 0);
        acc[mf][nf] = __builtin_amdgcn_mfma_f32_16x16x32_bf16(a0h, wbl[nf][0], acc[mf][nf], 0, 0, 0);
      }
#pragma unroll
      for (int nf = 0; nf < 4; ++nf) {
        acc[mf][nf] = __builtin_amdgcn_mfma_f32_16x16x32_bf16(a1h, wbh[nf][1], acc[mf][nf], 0, 0, 0);
        acc[mf][nf] = __builtin_amdgcn_mfma_f32_16x16x32_bf16(a1l, wbh[nf][1], acc[mf][nf], 0, 0, 0);
        acc[mf][nf] = __builtin_amdgcn_mfma_f32_16x16x32_bf16(a1h, wbl[nf][1], acc[mf][nf], 0, 0, 0);
      }
    }
  }
#pragma unroll
  for (int nf = 0; nf < 4; ++nf) {
    const int o = 16 * nf + (lane & 15);
    const float so = s2v[o], bo = b2v[o];
#pragma unroll
    for (int pt = 0; pt < 2; ++pt) {
      float v = -3.4e38f;
#pragma unroll
      for (int f = 0; f < 2; ++f) {
        const int mf = pt * 2 + f;
#pragma unroll
        for (int r = 0; r < 4; ++r) v = fmaxf(v, lrelu(fmaf(so, acc[mf][nf][r], bo)));
      }
      v = fmaxf(v, __shfl_xor(v, 16, 64));
      v = fmaxf(v, __shfl_xor(v, 32, 64));
      if ((lane >> 4) == 0) outC[((long long)b * 64 + o) * PTS + n0 + pt] = v;
    }
  }
}

// ---------------- edge3: gather-max of lrelu(P+Q), f32 PQ ----------------
__global__ __launch_bounds__(256) void edge3f_k(const float* __restrict__ PQ,
                                                const int* __restrict__ idxb, float* __restrict__ outC) {
  const int lane = threadIdx.x & 63, wid = threadIdx.x >> 6;
  const int g = blockIdx.x;
  const int b = g >> 6, n0 = ((g & 63) << 5) + (wid << 3);
  const float* Pb = PQ + (long long)b * PTS * 128;
  for (int pt = 0; pt < 8; ++pt) {
    const int n = n0 + pt;
    const float qv = Pb[n * 128 + 64 + lane];
    const int* ir = idxb + ((long long)b * PTS + n) * KK;
    float gm = -3.4e38f;
#pragma unroll 4
    for (int j = 0; j < KK; ++j) {
      const int m = ir[j];
      gm = fmaxf(gm, lrelu(Pb[m * 128 + lane] + qv));
    }
    outC[((long long)b * 64 + lane) * PTS + n] = gm;
  }
}

// ---------------- bf16 MFMA GEMM, optional split-bf16 3-pass ----------------
// MODE 0: affine+lrelu -> [b][O][PTS] (+tadd) | MODE 1: affine+lrelu, max over n -> gpart
// MODE 2: affine+lrelu -> [b][PTS][O] f32     | MODE 3: affine only -> f32 [b][PTS][O]
struct SrcTab { const float* p[4]; long long bs[4]; };

template <int MODE, int SPLIT>
__global__ __launch_bounds__(256) void mfgemm_k(
    const float* __restrict__ W, int wstride, int c0, SrcTab tab, int C,
    const float* __restrict__ sv, const float* __restrict__ bv, const float* __restrict__ tadd,
    float* __restrict__ out, int O) {
  __shared__ __align__(16) short Wl[(1 + SPLIT) * 128 * 32];
  __shared__ __align__(16) short Xl[(1 + SPLIT) * 128 * 32];
  __shared__ float red[2][128];
  const int tid = threadIdx.x, lane = tid & 63, wid = tid >> 6;
  const int nt = blockIdx.x, ot = blockIdx.y, b = blockIdx.z;
  const int n0 = nt * 128, o0 = ot * 128;
  const int wm = wid >> 1, wn = wid & 1;
  f32x4 acc[4][4] = {};
  for (int cc = 0; cc < C; cc += 32) {
    __syncthreads();
    {
      const int o = tid >> 1, hf = tid & 1;
      const float* src = &W[(long long)(o0 + o) * wstride + c0 + cc + hf * 16];
      const float4 v0 = *(const float4*)src;
      const float4 v1 = *(const float4*)(src + 4);
      const float4 v2 = *(const float4*)(src + 8);
      const float4 v3 = *(const float4*)(src + 12);
      uint4 d0, d1;
      d0.x = cvt2(v0.x, v0.y); d0.y = cvt2(v0.z, v0.w);
      d0.z = cvt2(v1.x, v1.y); d0.w = cvt2(v1.z, v1.w);
      d1.x = cvt2(v2.x, v2.y); d1.y = cvt2(v2.z, v2.w);
      d1.z = cvt2(v3.x, v3.y); d1.w = cvt2(v3.z, v3.w);
      *(uint4*)&Wl[o * 32 + swz(o, hf * 2) * 8] = d0;
      *(uint4*)&Wl[o * 32 + swz(o, hf * 2 + 1) * 8] = d1;
      if (SPLIT) {
        uint4 e0, e1;
        e0.x = cvt2lo(v0.x, v0.y, d0.x); e0.y = cvt2lo(v0.z, v0.w, d0.y);
        e0.z = cvt2lo(v1.x, v1.y, d0.z); e0.w = cvt2lo(v1.z, v1.w, d0.w);
        e1.x = cvt2lo(v2.x, v2.y, d1.x); e1.y = cvt2lo(v2.z, v2.w, d1.y);
        e1.z = cvt2lo(v3.x, v3.y, d1.z); e1.w = cvt2lo(v3.z, v3.w, d1.w);
        *(uint4*)&Wl[4096 + o * 32 + swz(o, hf * 2) * 8] = e0;
        *(uint4*)&Wl[4096 + o * 32 + swz(o, hf * 2 + 1) * 8] = e1;
      }
    }
    {
      const int n = tid & 127, ch = (tid >> 7) * 16;
      float val[16];
#pragma unroll
      for (int i = 0; i < 16; ++i) {
        const int cg = cc + ch + i;
        val[i] = tab.p[cg >> 6][tab.bs[cg >> 6] * b + (long long)(cg & 63) * PTS + n0 + n];
      }
      uint4 d0, d1;
      d0.x = cvt2(val[0], val[1]);   d0.y = cvt2(val[2], val[3]);
      d0.z = cvt2(val[4], val[5]);   d0.w = cvt2(val[6], val[7]);
      d1.x = cvt2(val[8], val[9]);   d1.y = cvt2(val[10], val[11]);
      d1.z = cvt2(val[12], val[13]); d1.w = cvt2(val[14], val[15]);
      const int s0 = ch >> 3;
      *(uint4*)&Xl[n * 32 + swz(n, s0) * 8] = d0;
      *(uint4*)&Xl[n * 32 + swz(n, s0 + 1) * 8] = d1;
      if (SPLIT) {
        uint4 e0, e1;
        e0.x = cvt2lo(val[0], val[1], d0.x);   e0.y = cvt2lo(val[2], val[3], d0.y);
        e0.z = cvt2lo(val[4], val[5], d0.z);   e0.w = cvt2lo(val[6], val[7], d0.w);
        e1.x = cvt2lo(val[8], val[9], d1.x);   e1.y = cvt2lo(val[10], val[11], d1.y);
        e1.z = cvt2lo(val[12], val[13], d1.z); e1.w = cvt2lo(val[14], val[15], d1.w);
        *(uint4*)&Xl[4096 + n * 32 + swz(n, s0) * 8] = e0;
        *(uint4*)&Xl[4096 + n * 32 + swz(n, s0 + 1) * 8] = e1;
      }
    }
    __syncthreads();
    bf8 afh[4], bfh[4], afl[4], bfl[4];
#pragma unroll
    for (int mf = 0; mf < 4; ++mf) {
      const int arow = wm * 64 + mf * 16 + (lane & 15);
      const int aoff = arow * 32 + swz(arow, lane >> 4) * 8;
      afh[mf] = *(const bf8*)&Wl[aoff];
      if (SPLIT) afl[mf] = *(const bf8*)&Wl[4096 + aoff];
    }
#pragma unroll
    for (int nf = 0; nf < 4; ++nf) {
      const int brow = wn * 64 + nf * 16 + (lane & 15);
      const int boff = brow * 32 + swz(brow, lane >> 4) * 8;
      bfh[nf] = *(const bf8*)&Xl[boff];
      if (SPLIT) bfl[nf] = *(const bf8*)&Xl[4096 + boff];
    }
#pragma unroll
    for (int mf = 0; mf < 4; ++mf)
#pragma unroll
      for (int nf = 0; nf < 4; ++nf) {
        acc[mf][nf] = __builtin_amdgcn_mfma_f32_16x16x32_bf16(afh[mf], bfh[nf], acc[mf][nf], 0, 0, 0);
        if (SPLIT) {
          acc[mf][nf] = __builtin_amdgcn_mfma_f32_16x16x32_bf16(afl[mf], bfh[nf], acc[mf][nf], 0, 0, 0);
          acc[mf][nf] = __builtin_amdgcn_mfma_f32_16x16x32_bf16(afh[mf], bfl[nf], acc[mf][nf], 0, 0, 0);
        }
      }
  }
  if (MODE == 1) {
#pragma unroll
    for (int mf = 0; mf < 4; ++mf)
#pragma unroll
      for (int r = 0; r < 4; ++r) {
        const int orl = wm * 64 + mf * 16 + (lane >> 4) * 4 + r;
        const int o = o0 + orl;
        const float s = sv[o], bb = bv[o];
        float v = -3.4e38f;
#pragma unroll
        for (int nf = 0; nf < 4; ++nf) v = fmaxf(v, lrelu(fmaf(s, acc[mf][nf][r], bb)));
        v = fmaxf(v, __shfl_xor(v, 1, 64));
        v = fmaxf(v, __shfl_xor(v, 2, 64));
        v = fmaxf(v, __shfl_xor(v, 4, 64));
        v = fmaxf(v, __shfl_xor(v, 8, 64));
        if ((lane & 15) == 0) red[wn][orl] = v;
      }
    __syncthreads();
    if (tid < 128) {
      const float m = fmaxf(red[0][tid], red[1][tid]);
      out[((long long)b * 16 + nt) * 1024 + o0 + tid] = m;
    }
  } else if (MODE == 0) {
#pragma unroll
    for (int mf = 0; mf < 4; ++mf)
#pragma unroll
      for (int r = 0; r < 4; ++r) {
        const int o = o0 + wm * 64 + mf * 16 + (lane >> 4) * 4 + r;
        const float s = sv[o], bb = bv[o];
        const float tv = (tadd != nullptr) ? tadd[(long long)b * O + o] : 0.f;
        float* op = out + ((long long)b * O + o) * PTS + n0 + wn * 64 + (lane & 15);
#pragma unroll
        for (int nf = 0; nf < 4; ++nf)
          op[nf * 16] = lrelu(fmaf(s, acc[mf][nf][r] + tv, bb));
      }
  } else if (MODE == 2) {
#pragma unroll
    for (int mf = 0; mf < 4; ++mf) {
      const int ob = wm * 64 + mf * 16 + (lane >> 4) * 4;
      float s4[4], b4[4];
#pragma unroll
      for (int r = 0; r < 4; ++r) { s4[r] = sv[o0 + ob + r]; b4[r] = bv[o0 + ob + r]; }
#pragma unroll
      for (int nf = 0; nf < 4; ++nf) {
        const int n = n0 + wn * 64 + nf * 16 + (lane & 15);
        float4 v;
        v.x = lrelu(fmaf(s4[0], acc[mf][nf][0], b4[0]));
        v.y = lrelu(fmaf(s4[1], acc[mf][nf][1], b4[1]));
        v.z = lrelu(fmaf(s4[2], acc[mf][nf][2], b4[2]));
        v.w = lrelu(fmaf(s4[3], acc[mf][nf][3], b4[3]));
        *(float4*)&out[((long long)b * PTS + n) * O + o0 + ob] = v;
      }
    }
  } else {  // MODE 3: affine only, f32 [b][PTS][O]
#pragma unroll
    for (int mf = 0; mf < 4; ++mf) {
      const int ob = wm * 64 + mf * 16 + (lane >> 4) * 4;
      float s4[4], b4[4];
#pragma unroll
      for (int r = 0; r < 4; ++r) { s4[r] = sv[o0 + ob + r]; b4[r] = bv[o0 + ob + r]; }
#pragma unroll
      for (int nf = 0; nf < 4; ++nf) {
        const int n = n0 + wn * 64 + nf * 16 + (lane & 15);
        float4 v;
        v.x = fmaf(s4[0], acc[mf][nf][0], b4[0]);
        v.y = fmaf(s4[1], acc[mf][nf][1], b4[1]);
        v.z = fmaf(s4[2], acc[mf][nf][2], b4[2]);
        v.w = fmaf(s4[3], acc[mf][nf][3], b4[3]);
        *(float4*)&out[((long long)b * PTS + n) * O + o0 + ob] = v;
      }
    }
  }
}

// ---------------- tvec (f32 exact; gfin folded: reads gpart) ----------------
__global__ __launch_bounds__(256) void tvec_k(
    const float* __restrict__ cls, const float* __restrict__ wc, const float* __restrict__ sc,
    const float* __restrict__ bc, const float* __restrict__ gp, const float* __restrict__ wf1,
    float* __restrict__ tvec) {
  __shared__ float gs[1024];
  __shared__ float cvs[64];
  const int b = blockIdx.x, tid = threadIdx.x;
  for (int q = tid; q < 1024; q += 256) {
    float m = -3.4e38f;
#pragma unroll 4
    for (int t = 0; t < 16; ++t) m = fmaxf(m, gp[((long long)b * 16 + t) * 1024 + q]);
    gs[q] = m;
  }
  if (tid < 64) {
    float a = 0.f;
#pragma unroll
    for (int j = 0; j < 16; ++j) a = fmaf(wc[tid * 16 + j], cls[b * 16 + j], a);
    cvs[tid] = lrelu(fmaf(sc[tid], a, bc[tid]));
  }
  __syncthreads();
  const float* wr = wf1 + (long long)tid * 1280;
  float a0 = 0.f, a1 = 0.f;
  for (int c = 0; c < 1024; c += 4) {
    const float4 w = *(const float4*)&wr[c];
    const float4 gv = *(const float4*)&gs[c];
    a0 = fmaf(w.x, gv.x, a0); a1 = fmaf(w.y, gv.y, a1);
    a0 = fmaf(w.z, gv.z, a0); a1 = fmaf(w.w, gv.w, a1);
  }
#pragma unroll
  for (int c = 0; c < 64; c += 4) {
    const float4 w = *(const float4*)&wr[1024 + c];
    const float4 cv = *(const float4*)&cvs[c];
    a0 = fmaf(w.x, cv.x, a0); a1 = fmaf(w.y, cv.y, a1);
    a0 = fmaf(w.z, cv.z, a0); a1 = fmaf(w.w, cv.w, a1);
  }
  tvec[b * 256 + tid] = a0 + a1;
}

// ---------------- logits + log_softmax ----------------
__global__ __launch_bounds__(256) void logits_k(const float* __restrict__ f3t, const float* __restrict__ wf4,
                                                float* __restrict__ out) {
  __shared__ float wT[6464];
  const int tid = threadIdx.x, lane = tid & 63, wv = tid >> 6;
  for (int q = tid; q < 6400; q += 256) {
    const int o = q >> 7, c = q & 127;
    wT[c * 50 + o] = wf4[q];
  }
  __syncthreads();
  const long long pn = (long long)blockIdx.x * 4 + wv;
  const float lo = f3t[pn * 128 + lane], hi = f3t[pn * 128 + 64 + lane];
  float a0 = 0.f, a1 = 0.f;
#pragma unroll
  for (int c = 0; c < 64; c += 2) {
    a0 = fmaf(wT[c * 50 + lane], rl(lo, c), a0);
    a1 = fmaf(wT[(c + 1) * 50 + lane], rl(lo, c + 1), a1);
  }
#pragma unroll
  for (int c = 0; c < 64; c += 2) {
    a0 = fmaf(wT[(64 + c) * 50 + lane], rl(hi, c), a0);
    a1 = fmaf(wT[(65 + c) * 50 + lane], rl(hi, c + 1), a1);
  }
  const float logit = (lane < 50) ? (a0 + a1) : -3.4e38f;
  float M = logit;
#pragma unroll
  for (int mask = 1; mask < 64; mask <<= 1) M = fmaxf(M, __shfl_xor(M, mask, 64));
  const float ex = (lane < 50) ? __expf(logit - M) : 0.f;
  float S = ex;
#pragma unroll
  for (int mask = 1; mask < 64; mask <<= 1) S += __shfl_xor(S, mask, 64);
  if (lane < 50) out[pn * 50 + lane] = logit - M - __logf(S);
}

extern "C" void kernel_launch(void* const* d_in, const int* in_sizes, int n_in,
                              void* d_out, int out_size, void* d_ws, size_t ws_size,
                              hipStream_t stream) {
  (void)in_sizes; (void)n_in; (void)out_size;
  const float* points = (const float*)d_in[0];
  const float* cls = (const float*)d_in[1];
  const float* w1 = (const float*)d_in[2];
  const float* s1 = (const float*)d_in[3];
  const float* b1 = (const float*)d_in[4];
  const float* w2 = (const float*)d_in[5];
  const float* s2 = (const float*)d_in[6];
  const float* b2 = (const float*)d_in[7];
  const float* w3 = (const float*)d_in[8];
  const float* s3 = (const float*)d_in[9];
  const float* b3 = (const float*)d_in[10];
  const float* w4 = (const float*)d_in[11];
  const float* s4 = (const float*)d_in[12];
  const float* b4 = (const float*)d_in[13];
  const float* w5 = (const float*)d_in[14];
  const float* s5 = (const float*)d_in[15];
  const float* b5 = (const float*)d_in[16];
  const float* w6 = (const float*)d_in[17];
  const float* s6 = (const float*)d_in[18];
  const float* b6 = (const float*)d_in[19];
  const float* wc = (const float*)d_in[20];
  const float* sc = (const float*)d_in[21];
  const float* bc = (const float*)d_in[22];
  const float* wf1 = (const float*)d_in[23];
  const float* sf1 = (const float*)d_in[24];
  const float* bf1 = (const float*)d_in[25];
  const float* wf2 = (const float*)d_in[26];
  const float* sf2 = (const float*)d_in[27];
  const float* bf2 = (const float*)d_in[28];
  const float* wf3 = (const float*)d_in[29];
  const float* sf3 = (const float*)d_in[30];
  const float* bf3 = (const float*)d_in[31];
  const float* wf4 = (const float*)d_in[32];
  float* out = (float*)d_out;
  float* ws = (float*)d_ws;

  // workspace (floats): x1c@0  x2c@2097152  x3c@4194304  f1c@8388608(..16777216)
  // PQf/f3t time-share f1c region; f2c aliases x*c (dead by then); aux @16777216+
  float* x1c = ws;
  float* x2c = ws + 2097152LL;
  float* x3c = ws + 4194304LL;
  float* f1c = ws + 8388608LL;
  float* f2c = ws;
  float* f3t = ws + 8388608LL;
  float* PQf = ws + 8388608LL;
  int* idx = (int*)(ws + 16777216LL);
  float* xxb = ws + 17432576LL;
  float* gpart = ws + 17465344LL;
  float* tvec = ws + 17743872LL;
  float* wc3 = ws + 17747968LL;
  float* sc3 = ws + 17756160LL;
  float* bc3 = ws + 17756288LL;
  float* wc5 = ws + 17756416LL;
  float* sc5 = ws + 17764608LL;
  float* bc5 = ws + 17764736LL;
  unsigned short* W2hi = (unsigned short*)(ws + 17764864LL);
  unsigned short* W2lo = (unsigned short*)(ws + 17766912LL);
  unsigned short* W4hi = (unsigned short*)(ws + 17768960LL);
  unsigned short* W4lo = (unsigned short*)(ws + 17771008LL);
  const long long staticEnd = 17773056LL;

  // D scratch: chunked by available ws. Fallback NB=2 time-shares the f1c region
  // (PQf/f3t are dead during every kNN phase).
  const long long DBATCH = (long long)PTS * PTS;  // 4194304 floats
  int NB; float* Dbuf;
  if (ws_size >= (size_t)(staticEnd + 16 * DBATCH) * 4) { NB = 16; Dbuf = ws + staticEnd; }
  else if (ws_size >= (size_t)(staticEnd + 4 * DBATCH) * 4) { NB = 4; Dbuf = ws + staticEnd; }
  else { NB = 2; Dbuf = ws + 8388608LL; }

  SrcTab tabX{{x1c, x2c, x3c, nullptr}, {64LL * PTS, 64LL * PTS, 64LL * PTS, 0}};
  SrcTab tabX1{{x1c, nullptr, nullptr, nullptr}, {64LL * PTS, 0, 0, 0}};
  SrcTab tabX2{{x2c, nullptr, nullptr, nullptr}, {64LL * PTS, 0, 0, 0}};
  SrcTab tabF1{{f1c, f1c + 64 * PTS, f1c + 128 * PTS, f1c + 192 * PTS},
               {256LL * PTS, 256LL * PTS, 256LL * PTS, 256LL * PTS}};
  SrcTab tabF2{{f2c, f2c + 64 * PTS, f2c + 128 * PTS, f2c + 192 * PTS},
               {256LL * PTS, 256LL * PTS, 256LL * PTS, 256LL * PTS}};

  prep_k<<<64, 256, 0, stream>>>(w3, s3, b3, w5, s5, b5, wc3, sc3, bc3, wc5, sc5, bc5);
  wsplit_k<<<32, 256, 0, stream>>>(w2, w4, W2hi, W2lo, W4hi, W4lo);

  // ---- kNN 1 (f32 exact) + edge1 (split-MFMA) ----
  xnorm_k<3><<<128, 256, 0, stream>>>(points, xxb);
  for (int bo = 0; bo < 16; bo += NB) {
    const int nb = (16 - bo < NB) ? (16 - bo) : NB;
    dist_k<3><<<dim3(16, 16, nb), 256, 0, stream>>>(points, xxb, Dbuf, bo);
    select_k<<<nb * 512, 256, 0, stream>>>(Dbuf, idx, bo);
  }
  pq1_k<<<8192, 256, 0, stream>>>(points, w1, s1, b1, PQf);
  edgemf_k<<<4096, 256, 0, stream>>>(PQf, idx, W2hi, W2lo, s2, b2, x1c);

  // ---- kNN 2 + edge2 (split-MFMA) ----
  xnorm_k<64><<<128, 256, 0, stream>>>(x1c, xxb);
  for (int bo = 0; bo < 16; bo += NB) {
    const int nb = (16 - bo < NB) ? (16 - bo) : NB;
    dist_k<64><<<dim3(16, 16, nb), 256, 0, stream>>>(x1c, xxb, Dbuf, bo);
    select_k<<<nb * 512, 256, 0, stream>>>(Dbuf, idx, bo);
  }
  mfgemm_k<3, 1><<<dim3(16, 1, 16), 256, 0, stream>>>(wc3, 64, 0, tabX1, 64, sc3, bc3, nullptr, PQf, 128);
  edgemf_k<<<4096, 256, 0, stream>>>(PQf, idx, W4hi, W4lo, s4, b4, x2c);

  // ---- kNN 3 + edge3 ----
  xnorm_k<64><<<128, 256, 0, stream>>>(x2c, xxb);
  for (int bo = 0; bo < 16; bo += NB) {
    const int nb = (16 - bo < NB) ? (16 - bo) : NB;
    dist_k<64><<<dim3(16, 16, nb), 256, 0, stream>>>(x2c, xxb, Dbuf, bo);
    select_k<<<nb * 512, 256, 0, stream>>>(Dbuf, idx, bo);
  }
  mfgemm_k<3, 1><<<dim3(16, 1, 16), 256, 0, stream>>>(wc5, 64, 0, tabX2, 64, sc5, bc5, nullptr, PQf, 128);
  edge3f_k<<<1024, 256, 0, stream>>>(PQf, idx, x3c);

  // ---- head (split-MFMA) ----
  mfgemm_k<1, 1><<<dim3(16, 8, 16), 256, 0, stream>>>(w6, 192, 0, tabX, 192, s6, b6, nullptr, gpart, 1024);
  tvec_k<<<16, 256, 0, stream>>>(cls, wc, sc, bc, gpart, wf1, tvec);
  mfgemm_k<0, 1><<<dim3(16, 2, 16), 256, 0, stream>>>(wf1, 1280, 1088, tabX, 192, sf1, bf1, tvec, f1c, 256);
  mfgemm_k<0, 1><<<dim3(16, 2, 16), 256, 0, stream>>>(wf2, 256, 0, tabF1, 256, sf2, bf2, nullptr, f2c, 256);
  mfgemm_k<2, 1><<<dim3(16, 1, 16), 256, 0, stream>>>(wf3, 256, 0, tabF2, 256, sf3, bf3, nullptr, f3t, 128);
  logits_k<<<8192, 256, 0, stream>>>(f3t, wf4, out);
}

// Round 9
// 1267.132 us; speedup vs baseline: 5.0505x; 1.2393x over previous
//
#include <hip/hip_runtime.h>

constexpr int PTS = 2048;   // points per batch
constexpr int KK  = 20;     // knn

typedef __attribute__((ext_vector_type(8))) short bf8;
typedef __attribute__((ext_vector_type(4))) float f32x4;

static __device__ __forceinline__ float lrelu(float x) { return fmaxf(x, 0.2f * x); }
static __device__ __forceinline__ float rl(float v, int l) {
  return __int_as_float(__builtin_amdgcn_readlane(__float_as_int(v), l));
}
static __device__ __forceinline__ unsigned cvt2(float lo, float hi) {
  unsigned r;
  asm("v_cvt_pk_bf16_f32 %0, %1, %2" : "=v"(r) : "v"(lo), "v"(hi));
  return r;
}
// residual after bf16-hi extraction: packs bf16(a - hi(a)), bf16(b - hi(b))
static __device__ __forceinline__ unsigned cvt2lo(float a, float b, unsigned h) {
  return cvt2(a - __uint_as_float(h << 16), b - __uint_as_float(h & 0xffff0000u));
}
static __device__ __forceinline__ unsigned short rne_bf16(float v) {
  unsigned u = __float_as_uint(v);
  return (unsigned short)((u + 0x7fffu + ((u >> 16) & 1u)) >> 16);
}
static __device__ __forceinline__ float bf2f(unsigned short u) {
  return __uint_as_float(((unsigned)u) << 16);
}
static __device__ __forceinline__ int swz(int row, int slot) {
  return slot ^ (row & 3) ^ ((row >> 2) & 3);   // 16B-slot swizzle, conflict-free
}
static __device__ __forceinline__ void argmax64(float& v, int& m) {
#pragma unroll
  for (int mask = 1; mask < 64; mask <<= 1) {
    float ov = __shfl_xor(v, mask, 64);
    int om = __shfl_xor(m, mask, 64);
    if (ov > v || (ov == v && om < m)) { v = ov; m = om; }
  }
}

// ---------------- xx[b][m] = sum_c x[c][m]^2 ----------------
template <int C>
__global__ __launch_bounds__(256) void xnorm_k(const float* __restrict__ x, float* __restrict__ xx) {
  const int i = blockIdx.x * 256 + threadIdx.x;
  const int b = i >> 11, m = i & 2047;
  float s = 0.f;
#pragma unroll
  for (int c = 0; c < C; ++c) {
    const float v = x[((long long)b * C + c) * PTS + m];
    s = fmaf(v, v, s);
  }
  xx[i] = s;
}

// ---------------- fused kNN v2: dist into LDS + proven LDS top-20 ----------------
// Block: 256 thr / 4 waves / 4 points. Wave w owns m-tiles {2w, 2w+1} for ALL 4 points.
// acc[4][2][4]: static-unrolled only (dist_k pattern, no spill). Distances LDS-resident.
// Distance = 2*sum_c xn*xm - xx[m], same fmaf chain order as dist_k (bitwise identical).
// m encode: m = (s>>2)*256 + 4*lane + (s&3), slot s = ascending-m within lane.
template <int C>
__global__ __launch_bounds__(256, 4) void fknn2_k(const float* __restrict__ x, const float* __restrict__ xx,
                                                  int* __restrict__ idxout) {
  __shared__ float dist[4][2112];
  __shared__ float xns[4][68];
  const int tid = threadIdx.x, lane = tid & 63, wid = tid >> 6;
  const int b = blockIdx.y;
  const int n0 = blockIdx.x * 4;

  // stage the 4 query points' features
  if (tid < 4 * C) {
    const int p = tid & 3, c = tid >> 2;
    xns[p][c] = x[((long long)b * C + c) * PTS + n0 + p];
  }
  __syncthreads();

  float acc[4][2][4] = {};  // [point][tt][i] — static indices only
  const float* px0 = x + (long long)b * C * PTS + (2 * wid) * 256 + 4 * lane;
  const float* px1 = px0 + 256;
#pragma unroll 4
  for (int c = 0; c < C; ++c) {
    const f32x4 v0 = *(const f32x4*)(px0 + (long long)c * PTS);
    const f32x4 v1 = *(const f32x4*)(px1 + (long long)c * PTS);
    const float xn0 = xns[0][c], xn1 = xns[1][c], xn2 = xns[2][c], xn3 = xns[3][c];
#pragma unroll
    for (int i = 0; i < 4; ++i) {
      acc[0][0][i] = fmaf(xn0, v0[i], acc[0][0][i]);
      acc[1][0][i] = fmaf(xn1, v0[i], acc[1][0][i]);
      acc[2][0][i] = fmaf(xn2, v0[i], acc[2][0][i]);
      acc[3][0][i] = fmaf(xn3, v0[i], acc[3][0][i]);
      acc[0][1][i] = fmaf(xn0, v1[i], acc[0][1][i]);
      acc[1][1][i] = fmaf(xn1, v1[i], acc[1][1][i]);
      acc[2][1][i] = fmaf(xn2, v1[i], acc[2][1][i]);
      acc[3][1][i] = fmaf(xn3, v1[i], acc[3][1][i]);
    }
  }
  // finalize d = 2*acc - xx[m]; write to LDS (banks: (lane + 8w+4tt+i)%32 -> 2-way, free)
#pragma unroll
  for (int tt = 0; tt < 2; ++tt) {
    const f32x4 xv = *(const f32x4*)&xx[b * 2048 + (2 * wid + tt) * 256 + 4 * lane];
#pragma unroll
    for (int p = 0; p < 4; ++p)
#pragma unroll
      for (int i = 0; i < 4; ++i)
        dist[p][lane * 33 + 8 * wid + 4 * tt + i] = 2.f * acc[p][tt][i] - xv[i];
  }
  __syncthreads();

  // selection: wave w -> point n0+w (proven select_k loop, remapped m-recovery)
  float* dp = dist[wid];
  const int n = n0 + wid;
  float bv = -3.4e38f; int bm = 1 << 29;
#pragma unroll 4
  for (int s = 0; s < 32; ++s) {
    const float v = dp[lane * 33 + s];
    if (v > bv) { bv = v; bm = ((s >> 2) << 8) + 4 * lane + (s & 3); }  // ascending m: keeps lowest
  }
  int keep = 0;
  for (int r = 0; r < KK; ++r) {
    float cv = bv; int cm = bm;
    argmax64(cv, cm);
    if (lane == r) keep = cm;
    const int ol = (cm >> 2) & 63;               // owner lane
    const int sl = ((cm >> 8) << 2) | (cm & 3);  // owner slot
    if (lane == 0) dp[ol * 33 + sl] = -3.4e38f;  // persistent invalidation
    asm volatile("s_waitcnt lgkmcnt(0)" ::: "memory");
    const int jj = lane & 31;                    // all-lane rescan of owner's slots
    float v2 = dp[ol * 33 + jj];
    int m2 = ((jj >> 2) << 8) + 4 * ol + (jj & 3);
    if (m2 == cm) v2 = -3.4e38f;
    argmax64(v2, m2);
    if (lane == ol) { bv = v2; bm = m2; }
  }
  if (lane < KK) idxout[((long long)b * PTS + n) * KK + lane] = keep;
}

// ---------------- prep: combined PQ weights (f32) for edge2/edge3 ----------------
__global__ __launch_bounds__(256) void prep_k(
    const float* __restrict__ w3, const float* __restrict__ s3, const float* __restrict__ b3,
    const float* __restrict__ w5, const float* __restrict__ s5, const float* __restrict__ b5,
    float* __restrict__ wc3, float* __restrict__ sc3, float* __restrict__ bc3,
    float* __restrict__ wc5, float* __restrict__ sc5, float* __restrict__ bc5) {
  const int i = blockIdx.x * 256 + threadIdx.x;  // 16384
  const int half = i >> 13;
  const int r = i & 8191;
  const float* w = half ? w5 : w3;
  float* wcp = half ? wc5 : wc3;
  const int o = r >> 6, c = r & 63;
  wcp[r] = (o < 64) ? w[o * 128 + c] : (w[(o - 64) * 128 + 64 + c] - w[(o - 64) * 128 + c]);
  if (r < 128) {
    const float* s = half ? s5 : s3;
    const float* bb = half ? b5 : b3;
    float* scp = half ? sc5 : sc3;
    float* bcp = half ? bc5 : bc3;
    scp[r] = s[r & 63];
    bcp[r] = (r < 64) ? 0.f : bb[r - 64];
  }
}

// ---------------- split conv2 weights to bf16 hi/lo ----------------
__global__ __launch_bounds__(256) void wsplit_k(const float* __restrict__ w2, const float* __restrict__ w4,
                                                unsigned short* __restrict__ W2hi, unsigned short* __restrict__ W2lo,
                                                unsigned short* __restrict__ W4hi, unsigned short* __restrict__ W4lo) {
  const int i = blockIdx.x * 256 + threadIdx.x;  // 8192
  const float v = (i < 4096) ? w2[i] : w4[i - 4096];
  const unsigned short h = rne_bf16(v);
  const unsigned short l = rne_bf16(v - bf2f(h));
  if (i < 4096) { W2hi[i] = h; W2lo[i] = l; }
  else { W4hi[i - 4096] = h; W4lo[i - 4096] = l; }
}

// ---------------- PQ for edge1 (f32 out, [b][n][128]: P=0..63, Q=64..127) ----------------
__global__ __launch_bounds__(256) void pq1_k(const float* __restrict__ pts,
    const float* __restrict__ w1, const float* __restrict__ s1, const float* __restrict__ b1,
    float* __restrict__ PQ) {
  const int i = blockIdx.x * 256 + threadIdx.x;  // 16*2048*64
  const int o = i & 63;
  const int bn = i >> 6;
  const int b = bn >> 11, n = bn & 2047;
  const float* pb = pts + (long long)b * 3 * PTS;
  const float x = pb[n], y = pb[PTS + n], z = pb[2 * PTS + n];
  const float s = s1[o];
  const float wa0 = w1[o * 6], wa1 = w1[o * 6 + 1], wa2 = w1[o * 6 + 2];
  const float wb0 = w1[o * 6 + 3], wb1 = w1[o * 6 + 4], wb2 = w1[o * 6 + 5];
  PQ[(long long)bn * 128 + o] = s * (wa0 * x + wa1 * y + wa2 * z);
  PQ[(long long)bn * 128 + 64 + o] =
      fmaf(s, (wb0 - wa0) * x + (wb1 - wa1) * y + (wb2 - wa2) * z, b1[o]);
}

// ---------------- MFMA EdgeConv (split-bf16 3-pass): conv2 as pair-GEMM, max over k ----------------
static __device__ __forceinline__ void mkfrag2(const float4 p0, const float4 p1,
                                               const float4 q0, const float4 q1,
                                               bf8& hi, bf8& lo) {
  const float y[8] = {p0.x + q0.x, p0.y + q0.y, p0.z + q0.z, p0.w + q0.w,
                      p1.x + q1.x, p1.y + q1.y, p1.z + q1.z, p1.w + q1.w};
  union { unsigned u[4]; bf8 v; } rh, rlo;
#pragma unroll
  for (int i = 0; i < 4; ++i) {
    const float a = lrelu(y[2 * i]), b = lrelu(y[2 * i + 1]);
    const unsigned h = cvt2(a, b);
    rh.u[i] = h;
    rlo.u[i] = cvt2lo(a, b, h);
  }
  hi = rh.v; lo = rlo.v;
}

__global__ __launch_bounds__(256) void edgemf_k(
    const float* __restrict__ PQ, const int* __restrict__ idxb,
    const unsigned short* __restrict__ Whi, const unsigned short* __restrict__ Wlo,
    const float* __restrict__ s2v, const float* __restrict__ b2v,
    float* __restrict__ outC) {
  const int lane = threadIdx.x & 63, wid = threadIdx.x >> 6;
  const int g = blockIdx.x;                 // 16b * 256
  const int b = g >> 8;
  const int n0 = (g & 255) * 8 + wid * 2;   // 8 pts/block, 2 per wave
  bf8 wbh[4][2], wbl[4][2];
#pragma unroll
  for (int nf = 0; nf < 4; ++nf)
#pragma unroll
    for (int kt = 0; kt < 2; ++kt) {
      const int off = (16 * nf + (lane & 15)) * 64 + kt * 32 + (lane >> 4) * 8;
      wbh[nf][kt] = *(const bf8*)&Whi[off];
      wbl[nf][kt] = *(const bf8*)&Wlo[off];
    }
  const float* Pb = PQ + (long long)b * PTS * 128;
  const int co = (lane >> 4) * 8;
  int mm[2][2];
  float4 qa[2][2], qb[2][2];
#pragma unroll
  for (int pt = 0; pt < 2; ++pt) {
    const int n = n0 + pt;
    const int* ir = idxb + ((long long)b * PTS + n) * KK;
    const int j1 = 16 + (lane & 15);
    mm[pt][0] = ir[lane & 15];
    mm[pt][1] = ir[j1 < KK ? j1 : 0];
    qa[pt][0] = *(const float4*)&Pb[n * 128 + 64 + co];
    qb[pt][0] = *(const float4*)&Pb[n * 128 + 68 + co];
    qa[pt][1] = *(const float4*)&Pb[n * 128 + 96 + co];
    qb[pt][1] = *(const float4*)&Pb[n * 128 + 100 + co];
  }
  f32x4 acc[4][4] = {};
#pragma unroll
  for (int pt = 0; pt < 2; ++pt) {
#pragma unroll
    for (int f = 0; f < 2; ++f) {
      const int m = mm[pt][f];
      const float4 p0a = *(const float4*)&Pb[m * 128 + co];
      const float4 p0b = *(const float4*)&Pb[m * 128 + 4 + co];
      const float4 p1a = *(const float4*)&Pb[m * 128 + 32 + co];
      const float4 p1b = *(const float4*)&Pb[m * 128 + 36 + co];
      bf8 a0h, a0l, a1h, a1l;
      mkfrag2(p0a, p0b, qa[pt][0], qb[pt][0], a0h, a0l);
      mkfrag2(p1a, p1b, qa[pt][1], qb[pt][1], a1h, a1l);
      const int mf = pt * 2 + f;
#pragma unroll
      for (int nf = 0; nf < 4; ++nf) {
        acc[mf][nf] = __builtin_amdgcn_mfma_f32_16x16x32_bf16(a0h, wbh[nf][0], acc[mf][nf], 0, 0, 0);
        acc[mf][nf] = __builtin_amdgcn_mfma_f32_16x16x32_bf16(a0l, wbh[nf][0], acc[mf][nf], 0, 0, 0);
        acc[mf][nf] = __builtin_amdgcn_mfma_f32_16x16x32_bf16(a0h, wbl[nf][0], acc[mf][nf], 0, 0, 0);
      }
#pragma unroll
      for (int nf = 0; nf < 4; ++nf) {
        acc[mf][nf] = __builtin_amdgcn_mfma_f32_16x16x32_bf16(a1h, wbh[nf][1], acc[mf][nf], 0, 0, 0);
        acc[mf][nf] = __builtin_amdgcn_mfma_f32_16x16x32_bf16(a1l, wbh[nf][1], acc[mf][nf], 0, 0, 0);
        acc[mf][nf] = __builtin_amdgcn_mfma_f32_16x16x32_bf16(a1h, wbl[nf][1], acc[mf][nf], 0, 0, 0);
      }
    }
  }
#pragma unroll
  for (int nf = 0; nf < 4; ++nf) {
    const int o = 16 * nf + (lane & 15);
    const float so = s2v[o], bo = b2v[o];
#pragma unroll
    for (int pt = 0; pt < 2; ++pt) {
      float v = -3.4e38f;
#pragma unroll
      for (int f = 0; f < 2; ++f) {
        const int mf = pt * 2 + f;
#pragma unroll
        for (int r = 0; r < 4; ++r) v = fmaxf(v, lrelu(fmaf(so, acc[mf][nf][r], bo)));
      }
      v = fmaxf(v, __shfl_xor(v, 16, 64));
      v = fmaxf(v, __shfl_xor(v, 32, 64));
      if ((lane >> 4) == 0) outC[((long long)b * 64 + o) * PTS + n0 + pt] = v;
    }
  }
}

// ---------------- edge3: gather-max of lrelu(P+Q), f32 PQ ----------------
__global__ __launch_bounds__(256) void edge3f_k(const float* __restrict__ PQ,
                                                const int* __restrict__ idxb, float* __restrict__ outC) {
  const int lane = threadIdx.x & 63, wid = threadIdx.x >> 6;
  const int g = blockIdx.x;
  const int b = g >> 6, n0 = ((g & 63) << 5) + (wid << 3);
  const float* Pb = PQ + (long long)b * PTS * 128;
  for (int pt = 0; pt < 8; ++pt) {
    const int n = n0 + pt;
    const float qv = Pb[n * 128 + 64 + lane];
    const int* ir = idxb + ((long long)b * PTS + n) * KK;
    float gm = -3.4e38f;
#pragma unroll 4
    for (int j = 0; j < KK; ++j) {
      const int m = ir[j];
      gm = fmaxf(gm, lrelu(Pb[m * 128 + lane] + qv));
    }
    outC[((long long)b * 64 + lane) * PTS + n] = gm;
  }
}

// ---------------- bf16 MFMA GEMM, optional split-bf16 3-pass ----------------
// MODE 0: affine+lrelu -> [b][O][PTS] (+tadd) | MODE 1: affine+lrelu, max over n -> gpart
// MODE 2: affine+lrelu -> [b][PTS][O] f32     | MODE 3: affine only -> f32 [b][PTS][O]
struct SrcTab { const float* p[4]; long long bs[4]; };

template <int MODE, int SPLIT>
__global__ __launch_bounds__(256) void mfgemm_k(
    const float* __restrict__ W, int wstride, int c0, SrcTab tab, int C,
    const float* __restrict__ sv, const float* __restrict__ bv, const float* __restrict__ tadd,
    float* __restrict__ out, int O) {
  __shared__ __align__(16) short Wl[(1 + SPLIT) * 128 * 32];
  __shared__ __align__(16) short Xl[(1 + SPLIT) * 128 * 32];
  __shared__ float red[2][128];
  const int tid = threadIdx.x, lane = tid & 63, wid = tid >> 6;
  const int nt = blockIdx.x, ot = blockIdx.y, b = blockIdx.z;
  const int n0 = nt * 128, o0 = ot * 128;
  const int wm = wid >> 1, wn = wid & 1;
  f32x4 acc[4][4] = {};
  for (int cc = 0; cc < C; cc += 32) {
    __syncthreads();
    {
      const int o = tid >> 1, hf = tid & 1;
      const float* src = &W[(long long)(o0 + o) * wstride + c0 + cc + hf * 16];
      const float4 v0 = *(const float4*)src;
      const float4 v1 = *(const float4*)(src + 4);
      const float4 v2 = *(const float4*)(src + 8);
      const float4 v3 = *(const float4*)(src + 12);
      uint4 d0, d1;
      d0.x = cvt2(v0.x, v0.y); d0.y = cvt2(v0.z, v0.w);
      d0.z = cvt2(v1.x, v1.y); d0.w = cvt2(v1.z, v1.w);
      d1.x = cvt2(v2.x, v2.y); d1.y = cvt2(v2.z, v2.w);
      d1.z = cvt2(v3.x, v3.y); d1.w = cvt2(v3.z, v3.w);
      *(uint4*)&Wl[o * 32 + swz(o, hf * 2) * 8] = d0;
      *(uint4*)&Wl[o * 32 + swz(o, hf * 2 + 1) * 8] = d1;
      if (SPLIT) {
        uint4 e0, e1;
        e0.x = cvt2lo(v0.x, v0.y, d0.x); e0.y = cvt2lo(v0.z, v0.w, d0.y);
        e0.z = cvt2lo(v1.x, v1.y, d0.z); e0.w = cvt2lo(v1.z, v1.w, d0.w);
        e1.x = cvt2lo(v2.x, v2.y, d1.x); e1.y = cvt2lo(v2.z, v2.w, d1.y);
        e1.z = cvt2lo(v3.x, v3.y, d1.z); e1.w = cvt2lo(v3.z, v3.w, d1.w);
        *(uint4*)&Wl[4096 + o * 32 + swz(o, hf * 2) * 8] = e0;
        *(uint4*)&Wl[4096 + o * 32 + swz(o, hf * 2 + 1) * 8] = e1;
      }
    }
    {
      const int n = tid & 127, ch = (tid >> 7) * 16;
      float val[16];
#pragma unroll
      for (int i = 0; i < 16; ++i) {
        const int cg = cc + ch + i;
        val[i] = tab.p[cg >> 6][tab.bs[cg >> 6] * b + (long long)(cg & 63) * PTS + n0 + n];
      }
      uint4 d0, d1;
      d0.x = cvt2(val[0], val[1]);   d0.y = cvt2(val[2], val[3]);
      d0.z = cvt2(val[4], val[5]);   d0.w = cvt2(val[6], val[7]);
      d1.x = cvt2(val[8], val[9]);   d1.y = cvt2(val[10], val[11]);
      d1.z = cvt2(val[12], val[13]); d1.w = cvt2(val[14], val[15]);
      const int s0 = ch >> 3;
      *(uint4*)&Xl[n * 32 + swz(n, s0) * 8] = d0;
      *(uint4*)&Xl[n * 32 + swz(n, s0 + 1) * 8] = d1;
      if (SPLIT) {
        uint4 e0, e1;
        e0.x = cvt2lo(val[0], val[1], d0.x);   e0.y = cvt2lo(val[2], val[3], d0.y);
        e0.z = cvt2lo(val[4], val[5], d0.z);   e0.w = cvt2lo(val[6], val[7], d0.w);
        e1.x = cvt2lo(val[8], val[9], d1.x);   e1.y = cvt2lo(val[10], val[11], d1.y);
        e1.z = cvt2lo(val[12], val[13], d1.z); e1.w = cvt2lo(val[14], val[15], d1.w);
        *(uint4*)&Xl[4096 + n * 32 + swz(n, s0) * 8] = e0;
        *(uint4*)&Xl[4096 + n * 32 + swz(n, s0 + 1) * 8] = e1;
      }
    }
    __syncthreads();
    bf8 afh[4], bfh[4], afl[4], bfl[4];
#pragma unroll
    for (int mf = 0; mf < 4; ++mf) {
      const int arow = wm * 64 + mf * 16 + (lane & 15);
      const int aoff = arow * 32 + swz(arow, lane >> 4) * 8;
      afh[mf] = *(const bf8*)&Wl[aoff];
      if (SPLIT) afl[mf] = *(const bf8*)&Wl[4096 + aoff];
    }
#pragma unroll
    for (int nf = 0; nf < 4; ++nf) {
      const int brow = wn * 64 + nf * 16 + (lane & 15);
      const int boff = brow * 32 + swz(brow, lane >> 4) * 8;
      bfh[nf] = *(const bf8*)&Xl[boff];
      if (SPLIT) bfl[nf] = *(const bf8*)&Xl[4096 + boff];
    }
#pragma unroll
    for (int mf = 0; mf < 4; ++mf)
#pragma unroll
      for (int nf = 0; nf < 4; ++nf) {
        acc[mf][nf] = __builtin_amdgcn_mfma_f32_16x16x32_bf16(afh[mf], bfh[nf], acc[mf][nf], 0, 0, 0);
        if (SPLIT) {
          acc[mf][nf] = __builtin_amdgcn_mfma_f32_16x16x32_bf16(afl[mf], bfh[nf], acc[mf][nf], 0, 0, 0);
          acc[mf][nf] = __builtin_amdgcn_mfma_f32_16x16x32_bf16(afh[mf], bfl[nf], acc[mf][nf], 0, 0, 0);
        }
      }
  }
  if (MODE == 1) {
#pragma unroll
    for (int mf = 0; mf < 4; ++mf)
#pragma unroll
      for (int r = 0; r < 4; ++r) {
        const int orl = wm * 64 + mf * 16 + (lane >> 4) * 4 + r;
        const int o = o0 + orl;
        const float s = sv[o], bb = bv[o];
        float v = -3.4e38f;
#pragma unroll
        for (int nf = 0; nf < 4; ++nf) v = fmaxf(v, lrelu(fmaf(s, acc[mf][nf][r], bb)));
        v = fmaxf(v, __shfl_xor(v, 1, 64));
        v = fmaxf(v, __shfl_xor(v, 2, 64));
        v = fmaxf(v, __shfl_xor(v, 4, 64));
        v = fmaxf(v, __shfl_xor(v, 8, 64));
        if ((lane & 15) == 0) red[wn][orl] = v;
      }
    __syncthreads();
    if (tid < 128) {
      const float m = fmaxf(red[0][tid], red[1][tid]);
      out[((long long)b * 16 + nt) * 1024 + o0 + tid] = m;
    }
  } else if (MODE == 0) {
#pragma unroll
    for (int mf = 0; mf < 4; ++mf)
#pragma unroll
      for (int r = 0; r < 4; ++r) {
        const int o = o0 + wm * 64 + mf * 16 + (lane >> 4) * 4 + r;
        const float s = sv[o], bb = bv[o];
        const float tv = (tadd != nullptr) ? tadd[(long long)b * O + o] : 0.f;
        float* op = out + ((long long)b * O + o) * PTS + n0 + wn * 64 + (lane & 15);
#pragma unroll
        for (int nf = 0; nf < 4; ++nf)
          op[nf * 16] = lrelu(fmaf(s, acc[mf][nf][r] + tv, bb));
      }
  } else if (MODE == 2) {
#pragma unroll
    for (int mf = 0; mf < 4; ++mf) {
      const int ob = wm * 64 + mf * 16 + (lane >> 4) * 4;
      float s4[4], b4[4];
#pragma unroll
      for (int r = 0; r < 4; ++r) { s4[r] = sv[o0 + ob + r]; b4[r] = bv[o0 + ob + r]; }
#pragma unroll
      for (int nf = 0; nf < 4; ++nf) {
        const int n = n0 + wn * 64 + nf * 16 + (lane & 15);
        float4 v;
        v.x = lrelu(fmaf(s4[0], acc[mf][nf][0], b4[0]));
        v.y = lrelu(fmaf(s4[1], acc[mf][nf][1], b4[1]));
        v.z = lrelu(fmaf(s4[2], acc[mf][nf][2], b4[2]));
        v.w = lrelu(fmaf(s4[3], acc[mf][nf][3], b4[3]));
        *(float4*)&out[((long long)b * PTS + n) * O + o0 + ob] = v;
      }
    }
  } else {  // MODE 3: affine only, f32 [b][PTS][O]
#pragma unroll
    for (int mf = 0; mf < 4; ++mf) {
      const int ob = wm * 64 + mf * 16 + (lane >> 4) * 4;
      float s4[4], b4[4];
#pragma unroll
      for (int r = 0; r < 4; ++r) { s4[r] = sv[o0 + ob + r]; b4[r] = bv[o0 + ob + r]; }
#pragma unroll
      for (int nf = 0; nf < 4; ++nf) {
        const int n = n0 + wn * 64 + nf * 16 + (lane & 15);
        float4 v;
        v.x = fmaf(s4[0], acc[mf][nf][0], b4[0]);
        v.y = fmaf(s4[1], acc[mf][nf][1], b4[1]);
        v.z = fmaf(s4[2], acc[mf][nf][2], b4[2]);
        v.w = fmaf(s4[3], acc[mf][nf][3], b4[3]);
        *(float4*)&out[((long long)b * PTS + n) * O + o0 + ob] = v;
      }
    }
  }
}

// ---------------- tvec (f32 exact; gfin folded: reads gpart) ----------------
__global__ __launch_bounds__(256) void tvec_k(
    const float* __restrict__ cls, const float* __restrict__ wc, const float* __restrict__ sc,
    const float* __restrict__ bc, const float* __restrict__ gp, const float* __restrict__ wf1,
    float* __restrict__ tvec) {
  __shared__ float gs[1024];
  __shared__ float cvs[64];
  const int b = blockIdx.x, tid = threadIdx.x;
  for (int q = tid; q < 1024; q += 256) {
    float m = -3.4e38f;
#pragma unroll 4
    for (int t = 0; t < 16; ++t) m = fmaxf(m, gp[((long long)b * 16 + t) * 1024 + q]);
    gs[q] = m;
  }
  if (tid < 64) {
    float a = 0.f;
#pragma unroll
    for (int j = 0; j < 16; ++j) a = fmaf(wc[tid * 16 + j], cls[b * 16 + j], a);
    cvs[tid] = lrelu(fmaf(sc[tid], a, bc[tid]));
  }
  __syncthreads();
  const float* wr = wf1 + (long long)tid * 1280;
  float a0 = 0.f, a1 = 0.f;
  for (int c = 0; c < 1024; c += 4) {
    const float4 w = *(const float4*)&wr[c];
    const float4 gv = *(const float4*)&gs[c];
    a0 = fmaf(w.x, gv.x, a0); a1 = fmaf(w.y, gv.y, a1);
    a0 = fmaf(w.z, gv.z, a0); a1 = fmaf(w.w, gv.w, a1);
  }
#pragma unroll
  for (int c = 0; c < 64; c += 4) {
    const float4 w = *(const float4*)&wr[1024 + c];
    const float4 cv = *(const float4*)&cvs[c];
    a0 = fmaf(w.x, cv.x, a0); a1 = fmaf(w.y, cv.y, a1);
    a0 = fmaf(w.z, cv.z, a0); a1 = fmaf(w.w, cv.w, a1);
  }
  tvec[b * 256 + tid] = a0 + a1;
}

// ---------------- logits + log_softmax ----------------
__global__ __launch_bounds__(256) void logits_k(const float* __restrict__ f3t, const float* __restrict__ wf4,
                                                float* __restrict__ out) {
  __shared__ float wT[6464];
  const int tid = threadIdx.x, lane = tid & 63, wv = tid >> 6;
  for (int q = tid; q < 6400; q += 256) {
    const int o = q >> 7, c = q & 127;
    wT[c * 50 + o] = wf4[q];
  }
  __syncthreads();
  const long long pn = (long long)blockIdx.x * 4 + wv;
  const float lo = f3t[pn * 128 + lane], hi = f3t[pn * 128 + 64 + lane];
  float a0 = 0.f, a1 = 0.f;
#pragma unroll
  for (int c = 0; c < 64; c += 2) {
    a0 = fmaf(wT[c * 50 + lane], rl(lo, c), a0);
    a1 = fmaf(wT[(c + 1) * 50 + lane], rl(lo, c + 1), a1);
  }
#pragma unroll
  for (int c = 0; c < 64; c += 2) {
    a0 = fmaf(wT[(64 + c) * 50 + lane], rl(hi, c), a0);
    a1 = fmaf(wT[(65 + c) * 50 + lane], rl(hi, c + 1), a1);
  }
  const float logit = (lane < 50) ? (a0 + a1) : -3.4e38f;
  float M = logit;
#pragma unroll
  for (int mask = 1; mask < 64; mask <<= 1) M = fmaxf(M, __shfl_xor(M, mask, 64));
  const float ex = (lane < 50) ? __expf(logit - M) : 0.f;
  float S = ex;
#pragma unroll
  for (int mask = 1; mask < 64; mask <<= 1) S += __shfl_xor(S, mask, 64);
  if (lane < 50) out[pn * 50 + lane] = logit - M - __logf(S);
}

extern "C" void kernel_launch(void* const* d_in, const int* in_sizes, int n_in,
                              void* d_out, int out_size, void* d_ws, size_t ws_size,
                              hipStream_t stream) {
  (void)in_sizes; (void)n_in; (void)out_size; (void)ws_size;
  const float* points = (const float*)d_in[0];
  const float* cls = (const float*)d_in[1];
  const float* w1 = (const float*)d_in[2];
  const float* s1 = (const float*)d_in[3];
  const float* b1 = (const float*)d_in[4];
  const float* w2 = (const float*)d_in[5];
  const float* s2 = (const float*)d_in[6];
  const float* b2 = (const float*)d_in[7];
  const float* w3 = (const float*)d_in[8];
  const float* s3 = (const float*)d_in[9];
  const float* b3 = (const float*)d_in[10];
  const float* w4 = (const float*)d_in[11];
  const float* s4 = (const float*)d_in[12];
  const float* b4 = (const float*)d_in[13];
  const float* w5 = (const float*)d_in[14];
  const float* s5 = (const float*)d_in[15];
  const float* b5 = (const float*)d_in[16];
  const float* w6 = (const float*)d_in[17];
  const float* s6 = (const float*)d_in[18];
  const float* b6 = (const float*)d_in[19];
  const float* wc = (const float*)d_in[20];
  const float* sc = (const float*)d_in[21];
  const float* bc = (const float*)d_in[22];
  const float* wf1 = (const float*)d_in[23];
  const float* sf1 = (const float*)d_in[24];
  const float* bf1 = (const float*)d_in[25];
  const float* wf2 = (const float*)d_in[26];
  const float* sf2 = (const float*)d_in[27];
  const float* bf2 = (const float*)d_in[28];
  const float* wf3 = (const float*)d_in[29];
  const float* sf3 = (const float*)d_in[30];
  const float* bf3 = (const float*)d_in[31];
  const float* wf4 = (const float*)d_in[32];
  float* out = (float*)d_out;
  float* ws = (float*)d_ws;

  // workspace (floats): x1c@0  x2c@2097152  x3c@4194304  f1c@8388608(..16777216)
  // PQf/f3t time-share f1c region; f2c aliases x*c (dead by then); aux @16777216+
  float* x1c = ws;
  float* x2c = ws + 2097152LL;
  float* x3c = ws + 4194304LL;
  float* f1c = ws + 8388608LL;
  float* f2c = ws;
  float* f3t = ws + 8388608LL;
  float* PQf = ws + 8388608LL;
  int* idx = (int*)(ws + 16777216LL);
  float* xxb = ws + 17432576LL;
  float* gpart = ws + 17465344LL;
  float* tvec = ws + 17743872LL;
  float* wc3 = ws + 17747968LL;
  float* sc3 = ws + 17756160LL;
  float* bc3 = ws + 17756288LL;
  float* wc5 = ws + 17756416LL;
  float* sc5 = ws + 17764608LL;
  float* bc5 = ws + 17764736LL;
  unsigned short* W2hi = (unsigned short*)(ws + 17764864LL);
  unsigned short* W2lo = (unsigned short*)(ws + 17766912LL);
  unsigned short* W4hi = (unsigned short*)(ws + 17768960LL);
  unsigned short* W4lo = (unsigned short*)(ws + 17771008LL);

  SrcTab tabX{{x1c, x2c, x3c, nullptr}, {64LL * PTS, 64LL * PTS, 64LL * PTS, 0}};
  SrcTab tabX1{{x1c, nullptr, nullptr, nullptr}, {64LL * PTS, 0, 0, 0}};
  SrcTab tabX2{{x2c, nullptr, nullptr, nullptr}, {64LL * PTS, 0, 0, 0}};
  SrcTab tabF1{{f1c, f1c + 64 * PTS, f1c + 128 * PTS, f1c + 192 * PTS},
               {256LL * PTS, 256LL * PTS, 256LL * PTS, 256LL * PTS}};
  SrcTab tabF2{{f2c, f2c + 64 * PTS, f2c + 128 * PTS, f2c + 192 * PTS},
               {256LL * PTS, 256LL * PTS, 256LL * PTS, 256LL * PTS}};

  prep_k<<<64, 256, 0, stream>>>(w3, s3, b3, w5, s5, b5, wc3, sc3, bc3, wc5, sc5, bc5);
  wsplit_k<<<32, 256, 0, stream>>>(w2, w4, W2hi, W2lo, W4hi, W4lo);

  // ---- kNN 1 (fused, f32 bitwise-exact) + edge1 (split-MFMA) ----
  xnorm_k<3><<<128, 256, 0, stream>>>(points, xxb);
  fknn2_k<3><<<dim3(512, 16), 256, 0, stream>>>(points, xxb, idx);
  pq1_k<<<8192, 256, 0, stream>>>(points, w1, s1, b1, PQf);
  edgemf_k<<<4096, 256, 0, stream>>>(PQf, idx, W2hi, W2lo, s2, b2, x1c);

  // ---- kNN 2 + edge2 (split-MFMA) ----
  xnorm_k<64><<<128, 256, 0, stream>>>(x1c, xxb);
  fknn2_k<64><<<dim3(512, 16), 256, 0, stream>>>(x1c, xxb, idx);
  mfgemm_k<3, 1><<<dim3(16, 1, 16), 256, 0, stream>>>(wc3, 64, 0, tabX1, 64, sc3, bc3, nullptr, PQf, 128);
  edgemf_k<<<4096, 256, 0, stream>>>(PQf, idx, W4hi, W4lo, s4, b4, x2c);

  // ---- kNN 3 + edge3 ----
  xnorm_k<64><<<128, 256, 0, stream>>>(x2c, xxb);
  fknn2_k<64><<<dim3(512, 16), 256, 0, stream>>>(x2c, xxb, idx);
  mfgemm_k<3, 1><<<dim3(16, 1, 16), 256, 0, stream>>>(wc5, 64, 0, tabX2, 64, sc5, bc5, nullptr, PQf, 128);
  edge3f_k<<<1024, 256, 0, stream>>>(PQf, idx, x3c);

  // ---- head (split-MFMA) ----
  mfgemm_k<1, 1><<<dim3(16, 8, 16), 256, 0, stream>>>(w6, 192, 0, tabX, 192, s6, b6, nullptr, gpart, 1024);
  tvec_k<<<16, 256, 0, stream>>>(cls, wc, sc, bc, gpart, wf1, tvec);
  mfgemm_k<0, 1><<<dim3(16, 2, 16), 256, 0, stream>>>(wf1, 1280, 1088, tabX, 192, sf1, bf1, tvec, f1c, 256);
  mfgemm_k<0, 1><<<dim3(16, 2, 16), 256, 0, stream>>>(wf2, 256, 0, tabF1, 256, sf2, bf2, nullptr, f2c, 256);
  mfgemm_k<2, 1><<<dim3(16, 1, 16), 256, 0, stream>>>(wf3, 256, 0, tabF2, 256, sf3, bf3, nullptr, f3t, 128);
  logits_k<<<8192, 256, 0, stream>>>(f3t, wf4, out);
}

// Round 10
// 1223.516 us; speedup vs baseline: 5.2306x; 1.0356x over previous
//
#include <hip/hip_runtime.h>

constexpr int PTS = 2048;   // points per batch
constexpr int KK  = 20;     // knn

typedef __attribute__((ext_vector_type(8))) short bf8;
typedef __attribute__((ext_vector_type(4))) float f32x4;

static __device__ __forceinline__ float lrelu(float x) { return fmaxf(x, 0.2f * x); }
static __device__ __forceinline__ float rl(float v, int l) {
  return __int_as_float(__builtin_amdgcn_readlane(__float_as_int(v), l));
}
static __device__ __forceinline__ unsigned cvt2(float lo, float hi) {
  unsigned r;
  asm("v_cvt_pk_bf16_f32 %0, %1, %2" : "=v"(r) : "v"(lo), "v"(hi));
  return r;
}
// residual after bf16-hi extraction: packs bf16(a - hi(a)), bf16(b - hi(b))
static __device__ __forceinline__ unsigned cvt2lo(float a, float b, unsigned h) {
  return cvt2(a - __uint_as_float(h << 16), b - __uint_as_float(h & 0xffff0000u));
}
static __device__ __forceinline__ unsigned short rne_bf16(float v) {
  unsigned u = __float_as_uint(v);
  return (unsigned short)((u + 0x7fffu + ((u >> 16) & 1u)) >> 16);
}
static __device__ __forceinline__ float bf2f(unsigned short u) {
  return __uint_as_float(((unsigned)u) << 16);
}
static __device__ __forceinline__ int swz(int row, int slot) {
  return slot ^ (row & 3) ^ ((row >> 2) & 3);   // 16B-slot swizzle, conflict-free
}
static __device__ __forceinline__ void argmax64(float& v, int& m) {
#pragma unroll
  for (int mask = 1; mask < 64; mask <<= 1) {
    float ov = __shfl_xor(v, mask, 64);
    int om = __shfl_xor(m, mask, 64);
    if (ov > v || (ov == v && om < m)) { v = ov; m = om; }
  }
}

// ---------------- xx[b][m] = sum_c x[c][m]^2 ----------------
template <int C>
__global__ __launch_bounds__(256) void xnorm_k(const float* __restrict__ x, float* __restrict__ xx) {
  const int i = blockIdx.x * 256 + threadIdx.x;
  const int b = i >> 11, m = i & 2047;
  float s = 0.f;
#pragma unroll
  for (int c = 0; c < C; ++c) {
    const float v = x[((long long)b * C + c) * PTS + m];
    s = fmaf(v, v, s);
  }
  xx[i] = s;
}

// ---------------- fused kNN v3: dist into LDS + named-scalar register top-20 ----------------
// Block: 256 thr / 4 waves / 4 points. Wave w owns m-tiles {2w, 2w+1} for ALL 4 points.
// Distance = 2*sum_c xn*xm - xx[m], same fmaf chain order as before (bitwise identical).
// Selection: lane loads its 32 slots into NAMED scalars (no arrays -> no spill path);
// per round: argmax64 -> uniform switch invalidation -> 31-op binary max tree.
// m encode: m = (s>>2)*256 + 4*lane + (s&3); ascending s = ascending m (ties: lower s wins).
template <int C>
__global__ __launch_bounds__(256, 4) void fknn3_k(const float* __restrict__ x, const float* __restrict__ xx,
                                                  int* __restrict__ idxout) {
  __shared__ float dist[4][2112];
  __shared__ float xns[4][68];
  const int tid = threadIdx.x, lane = tid & 63, wid = tid >> 6;
  const int b = blockIdx.y;
  const int n0 = blockIdx.x * 4;

  if (tid < 4 * C) {
    const int p = tid & 3, c = tid >> 2;
    xns[p][c] = x[((long long)b * C + c) * PTS + n0 + p];
  }
  __syncthreads();

  float acc[4][2][4] = {};  // [point][tt][i] — static indices only
  const float* px0 = x + (long long)b * C * PTS + (2 * wid) * 256 + 4 * lane;
  const float* px1 = px0 + 256;
#pragma unroll 4
  for (int c = 0; c < C; ++c) {
    const f32x4 v0 = *(const f32x4*)(px0 + (long long)c * PTS);
    const f32x4 v1 = *(const f32x4*)(px1 + (long long)c * PTS);
    const float xn0 = xns[0][c], xn1 = xns[1][c], xn2 = xns[2][c], xn3 = xns[3][c];
#pragma unroll
    for (int i = 0; i < 4; ++i) {
      acc[0][0][i] = fmaf(xn0, v0[i], acc[0][0][i]);
      acc[1][0][i] = fmaf(xn1, v0[i], acc[1][0][i]);
      acc[2][0][i] = fmaf(xn2, v0[i], acc[2][0][i]);
      acc[3][0][i] = fmaf(xn3, v0[i], acc[3][0][i]);
      acc[0][1][i] = fmaf(xn0, v1[i], acc[0][1][i]);
      acc[1][1][i] = fmaf(xn1, v1[i], acc[1][1][i]);
      acc[2][1][i] = fmaf(xn2, v1[i], acc[2][1][i]);
      acc[3][1][i] = fmaf(xn3, v1[i], acc[3][1][i]);
    }
  }
#pragma unroll
  for (int tt = 0; tt < 2; ++tt) {
    const f32x4 xv = *(const f32x4*)&xx[b * 2048 + (2 * wid + tt) * 256 + 4 * lane];
#pragma unroll
    for (int p = 0; p < 4; ++p)
#pragma unroll
      for (int i = 0; i < 4; ++i)
        dist[p][lane * 33 + 8 * wid + 4 * tt + i] = 2.f * acc[p][tt][i] - xv[i];
  }
  __syncthreads();

  // ---- selection: wave w -> point n0+w ----
  const float NEG = -3.4e38f;
  float* dp = dist[wid];
  const int n = n0 + wid;
#define LDD(r) float d##r = dp[lane * 33 + r];
  LDD(0) LDD(1) LDD(2) LDD(3) LDD(4) LDD(5) LDD(6) LDD(7)
  LDD(8) LDD(9) LDD(10) LDD(11) LDD(12) LDD(13) LDD(14) LDD(15)
  LDD(16) LDD(17) LDD(18) LDD(19) LDD(20) LDD(21) LDD(22) LDD(23)
  LDD(24) LDD(25) LDD(26) LDD(27) LDD(28) LDD(29) LDD(30) LDD(31)
#undef LDD

#define P2(vA, iA, vB, iB, vO, iO) float vO = vA; int iO = iA; if (vB > vA) { vO = vB; iO = iB; }
#define TREE32(bvout, bmout)                                                            \
  {                                                                                     \
    P2(d0, 0, d1, 1, e0, j0) P2(d2, 2, d3, 3, e1, j1) P2(d4, 4, d5, 5, e2, j2)          \
    P2(d6, 6, d7, 7, e3, j3) P2(d8, 8, d9, 9, e4, j4) P2(d10, 10, d11, 11, e5, j5)      \
    P2(d12, 12, d13, 13, e6, j6) P2(d14, 14, d15, 15, e7, j7)                           \
    P2(d16, 16, d17, 17, e8, j8) P2(d18, 18, d19, 19, e9, j9)                           \
    P2(d20, 20, d21, 21, e10, j10) P2(d22, 22, d23, 23, e11, j11)                       \
    P2(d24, 24, d25, 25, e12, j12) P2(d26, 26, d27, 27, e13, j13)                       \
    P2(d28, 28, d29, 29, e14, j14) P2(d30, 30, d31, 31, e15, j15)                       \
    P2(e0, j0, e1, j1, f0, k0) P2(e2, j2, e3, j3, f1, k1)                               \
    P2(e4, j4, e5, j5, f2, k2) P2(e6, j6, e7, j7, f3, k3)                               \
    P2(e8, j8, e9, j9, f4, k4) P2(e10, j10, e11, j11, f5, k5)                           \
    P2(e12, j12, e13, j13, f6, k6) P2(e14, j14, e15, j15, f7, k7)                       \
    P2(f0, k0, f1, k1, g0, l0) P2(f2, k2, f3, k3, g1, l1)                               \
    P2(f4, k4, f5, k5, g2, l2) P2(f6, k6, f7, k7, g3, l3)                               \
    P2(g0, l0, g1, l1, h0, q0) P2(g2, l2, g3, l3, h1, q1)                               \
    P2(h0, q0, h1, q1, tf, ti)                                                          \
    bvout = tf;                                                                         \
    bmout = ((ti >> 2) << 8) + 4 * lane + (ti & 3);                                     \
  }

  float bv; int bm;
  TREE32(bv, bm)
  int keep = 0;
  for (int rd = 0; rd < KK; ++rd) {
    float cv = bv; int cm = bm;
    argmax64(cv, cm);
    if (lane == rd) keep = cm;
    const int ol = (cm >> 2) & 63;               // owner lane (per-wave uniform)
    const int sl = ((cm >> 8) << 2) | (cm & 3);  // owner slot (per-wave uniform)
    const bool own = (lane == ol);
#define CINV(r) case r: if (own) d##r = NEG; break;
    switch (sl) {
      CINV(0) CINV(1) CINV(2) CINV(3) CINV(4) CINV(5) CINV(6) CINV(7)
      CINV(8) CINV(9) CINV(10) CINV(11) CINV(12) CINV(13) CINV(14) CINV(15)
      CINV(16) CINV(17) CINV(18) CINV(19) CINV(20) CINV(21) CINV(22) CINV(23)
      CINV(24) CINV(25) CINV(26) CINV(27) CINV(28) CINV(29) CINV(30) CINV(31)
    }
#undef CINV
    float nbv; int nbm;
    TREE32(nbv, nbm)
    if (own) { bv = nbv; bm = nbm; }
  }
#undef TREE32
#undef P2
  if (lane < KK) idxout[((long long)b * PTS + n) * KK + lane] = keep;
}

// ---------------- prep: combined PQ weights (f32) for edge2/edge3 ----------------
__global__ __launch_bounds__(256) void prep_k(
    const float* __restrict__ w3, const float* __restrict__ s3, const float* __restrict__ b3,
    const float* __restrict__ w5, const float* __restrict__ s5, const float* __restrict__ b5,
    float* __restrict__ wc3, float* __restrict__ sc3, float* __restrict__ bc3,
    float* __restrict__ wc5, float* __restrict__ sc5, float* __restrict__ bc5) {
  const int i = blockIdx.x * 256 + threadIdx.x;  // 16384
  const int half = i >> 13;
  const int r = i & 8191;
  const float* w = half ? w5 : w3;
  float* wcp = half ? wc5 : wc3;
  const int o = r >> 6, c = r & 63;
  wcp[r] = (o < 64) ? w[o * 128 + c] : (w[(o - 64) * 128 + 64 + c] - w[(o - 64) * 128 + c]);
  if (r < 128) {
    const float* s = half ? s5 : s3;
    const float* bb = half ? b5 : b3;
    float* scp = half ? sc5 : sc3;
    float* bcp = half ? bc5 : bc3;
    scp[r] = s[r & 63];
    bcp[r] = (r < 64) ? 0.f : bb[r - 64];
  }
}

// ---------------- split conv2 weights to bf16 hi/lo ----------------
__global__ __launch_bounds__(256) void wsplit_k(const float* __restrict__ w2, const float* __restrict__ w4,
                                                unsigned short* __restrict__ W2hi, unsigned short* __restrict__ W2lo,
                                                unsigned short* __restrict__ W4hi, unsigned short* __restrict__ W4lo) {
  const int i = blockIdx.x * 256 + threadIdx.x;  // 8192
  const float v = (i < 4096) ? w2[i] : w4[i - 4096];
  const unsigned short h = rne_bf16(v);
  const unsigned short l = rne_bf16(v - bf2f(h));
  if (i < 4096) { W2hi[i] = h; W2lo[i] = l; }
  else { W4hi[i - 4096] = h; W4lo[i - 4096] = l; }
}

// ---------------- PQ for edge1 (f32 out, [b][n][128]: P=0..63, Q=64..127) ----------------
__global__ __launch_bounds__(256) void pq1_k(const float* __restrict__ pts,
    const float* __restrict__ w1, const float* __restrict__ s1, const float* __restrict__ b1,
    float* __restrict__ PQ) {
  const int i = blockIdx.x * 256 + threadIdx.x;  // 16*2048*64
  const int o = i & 63;
  const int bn = i >> 6;
  const int b = bn >> 11, n = bn & 2047;
  const float* pb = pts + (long long)b * 3 * PTS;
  const float x = pb[n], y = pb[PTS + n], z = pb[2 * PTS + n];
  const float s = s1[o];
  const float wa0 = w1[o * 6], wa1 = w1[o * 6 + 1], wa2 = w1[o * 6 + 2];
  const float wb0 = w1[o * 6 + 3], wb1 = w1[o * 6 + 4], wb2 = w1[o * 6 + 5];
  PQ[(long long)bn * 128 + o] = s * (wa0 * x + wa1 * y + wa2 * z);
  PQ[(long long)bn * 128 + 64 + o] =
      fmaf(s, (wb0 - wa0) * x + (wb1 - wa1) * y + (wb2 - wa2) * z, b1[o]);
}

// ---------------- MFMA EdgeConv (split-bf16 3-pass): conv2 as pair-GEMM, max over k ----------------
static __device__ __forceinline__ void mkfrag2(const float4 p0, const float4 p1,
                                               const float4 q0, const float4 q1,
                                               bf8& hi, bf8& lo) {
  const float y[8] = {p0.x + q0.x, p0.y + q0.y, p0.z + q0.z, p0.w + q0.w,
                      p1.x + q1.x, p1.y + q1.y, p1.z + q1.z, p1.w + q1.w};
  union { unsigned u[4]; bf8 v; } rh, rlo;
#pragma unroll
  for (int i = 0; i < 4; ++i) {
    const float a = lrelu(y[2 * i]), b = lrelu(y[2 * i + 1]);
    const unsigned h = cvt2(a, b);
    rh.u[i] = h;
    rlo.u[i] = cvt2lo(a, b, h);
  }
  hi = rh.v; lo = rlo.v;
}

__global__ __launch_bounds__(256) void edgemf_k(
    const float* __restrict__ PQ, const int* __restrict__ idxb,
    const unsigned short* __restrict__ Whi, const unsigned short* __restrict__ Wlo,
    const float* __restrict__ s2v, const float* __restrict__ b2v,
    float* __restrict__ outC) {
  const int lane = threadIdx.x & 63, wid = threadIdx.x >> 6;
  const int g = blockIdx.x;                 // 16b * 256
  const int b = g >> 8;
  const int n0 = (g & 255) * 8 + wid * 2;   // 8 pts/block, 2 per wave
  bf8 wbh[4][2], wbl[4][2];
#pragma unroll
  for (int nf = 0; nf < 4; ++nf)
#pragma unroll
    for (int kt = 0; kt < 2; ++kt) {
      const int off = (16 * nf + (lane & 15)) * 64 + kt * 32 + (lane >> 4) * 8;
      wbh[nf][kt] = *(const bf8*)&Whi[off];
      wbl[nf][kt] = *(const bf8*)&Wlo[off];
    }
  const float* Pb = PQ + (long long)b * PTS * 128;
  const int co = (lane >> 4) * 8;
  int mm[2][2];
  float4 qa[2][2], qb[2][2];
#pragma unroll
  for (int pt = 0; pt < 2; ++pt) {
    const int n = n0 + pt;
    const int* ir = idxb + ((long long)b * PTS + n) * KK;
    const int j1 = 16 + (lane & 15);
    mm[pt][0] = ir[lane & 15];
    mm[pt][1] = ir[j1 < KK ? j1 : 0];
    qa[pt][0] = *(const float4*)&Pb[n * 128 + 64 + co];
    qb[pt][0] = *(const float4*)&Pb[n * 128 + 68 + co];
    qa[pt][1] = *(const float4*)&Pb[n * 128 + 96 + co];
    qb[pt][1] = *(const float4*)&Pb[n * 128 + 100 + co];
  }
  f32x4 acc[4][4] = {};
#pragma unroll
  for (int pt = 0; pt < 2; ++pt) {
#pragma unroll
    for (int f = 0; f < 2; ++f) {
      const int m = mm[pt][f];
      const float4 p0a = *(const float4*)&Pb[m * 128 + co];
      const float4 p0b = *(const float4*)&Pb[m * 128 + 4 + co];
      const float4 p1a = *(const float4*)&Pb[m * 128 + 32 + co];
      const float4 p1b = *(const float4*)&Pb[m * 128 + 36 + co];
      bf8 a0h, a0l, a1h, a1l;
      mkfrag2(p0a, p0b, qa[pt][0], qb[pt][0], a0h, a0l);
      mkfrag2(p1a, p1b, qa[pt][1], qb[pt][1], a1h, a1l);
      const int mf = pt * 2 + f;
#pragma unroll
      for (int nf = 0; nf < 4; ++nf) {
        acc[mf][nf] = __builtin_amdgcn_mfma_f32_16x16x32_bf16(a0h, wbh[nf][0], acc[mf][nf], 0, 0, 0);
        acc[mf][nf] = __builtin_amdgcn_mfma_f32_16x16x32_bf16(a0l, wbh[nf][0], acc[mf][nf], 0, 0, 0);
        acc[mf][nf] = __builtin_amdgcn_mfma_f32_16x16x32_bf16(a0h, wbl[nf][0], acc[mf][nf], 0, 0, 0);
      }
#pragma unroll
      for (int nf = 0; nf < 4; ++nf) {
        acc[mf][nf] = __builtin_amdgcn_mfma_f32_16x16x32_bf16(a1h, wbh[nf][1], acc[mf][nf], 0, 0, 0);
        acc[mf][nf] = __builtin_amdgcn_mfma_f32_16x16x32_bf16(a1l, wbh[nf][1], acc[mf][nf], 0, 0, 0);
        acc[mf][nf] = __builtin_amdgcn_mfma_f32_16x16x32_bf16(a1h, wbl[nf][1], acc[mf][nf], 0, 0, 0);
      }
    }
  }
#pragma unroll
  for (int nf = 0; nf < 4; ++nf) {
    const int o = 16 * nf + (lane & 15);
    const float so = s2v[o], bo = b2v[o];
#pragma unroll
    for (int pt = 0; pt < 2; ++pt) {
      float v = -3.4e38f;
#pragma unroll
      for (int f = 0; f < 2; ++f) {
        const int mf = pt * 2 + f;
#pragma unroll
        for (int r = 0; r < 4; ++r) v = fmaxf(v, lrelu(fmaf(so, acc[mf][nf][r], bo)));
      }
      v = fmaxf(v, __shfl_xor(v, 16, 64));
      v = fmaxf(v, __shfl_xor(v, 32, 64));
      if ((lane >> 4) == 0) outC[((long long)b * 64 + o) * PTS + n0 + pt] = v;
    }
  }
}

// ---------------- edge3: gather-max of lrelu(P+Q), f32 PQ ----------------
__global__ __launch_bounds__(256) void edge3f_k(const float* __restrict__ PQ,
                                                const int* __restrict__ idxb, float* __restrict__ outC) {
  const int lane = threadIdx.x & 63, wid = threadIdx.x >> 6;
  const int g = blockIdx.x;
  const int b = g >> 6, n0 = ((g & 63) << 5) + (wid << 3);
  const float* Pb = PQ + (long long)b * PTS * 128;
  for (int pt = 0; pt < 8; ++pt) {
    const int n = n0 + pt;
    const float qv = Pb[n * 128 + 64 + lane];
    const int* ir = idxb + ((long long)b * PTS + n) * KK;
    float gm = -3.4e38f;
#pragma unroll 4
    for (int j = 0; j < KK; ++j) {
      const int m = ir[j];
      gm = fmaxf(gm, lrelu(Pb[m * 128 + lane] + qv));
    }
    outC[((long long)b * 64 + lane) * PTS + n] = gm;
  }
}

// ---------------- bf16 MFMA GEMM, optional split-bf16 3-pass ----------------
// MODE 0: affine+lrelu -> [b][O][PTS] (+tadd) | MODE 1: affine+lrelu, max over n -> gpart
// MODE 2: affine+lrelu -> [b][PTS][O] f32     | MODE 3: affine only -> f32 [b][PTS][O]
struct SrcTab { const float* p[4]; long long bs[4]; };

template <int MODE, int SPLIT>
__global__ __launch_bounds__(256) void mfgemm_k(
    const float* __restrict__ W, int wstride, int c0, SrcTab tab, int C,
    const float* __restrict__ sv, const float* __restrict__ bv, const float* __restrict__ tadd,
    float* __restrict__ out, int O) {
  __shared__ __align__(16) short Wl[(1 + SPLIT) * 128 * 32];
  __shared__ __align__(16) short Xl[(1 + SPLIT) * 128 * 32];
  __shared__ float red[2][128];
  const int tid = threadIdx.x, lane = tid & 63, wid = tid >> 6;
  const int nt = blockIdx.x, ot = blockIdx.y, b = blockIdx.z;
  const int n0 = nt * 128, o0 = ot * 128;
  const int wm = wid >> 1, wn = wid & 1;
  f32x4 acc[4][4] = {};
  for (int cc = 0; cc < C; cc += 32) {
    __syncthreads();
    {
      const int o = tid >> 1, hf = tid & 1;
      const float* src = &W[(long long)(o0 + o) * wstride + c0 + cc + hf * 16];
      const float4 v0 = *(const float4*)src;
      const float4 v1 = *(const float4*)(src + 4);
      const float4 v2 = *(const float4*)(src + 8);
      const float4 v3 = *(const float4*)(src + 12);
      uint4 d0, d1;
      d0.x = cvt2(v0.x, v0.y); d0.y = cvt2(v0.z, v0.w);
      d0.z = cvt2(v1.x, v1.y); d0.w = cvt2(v1.z, v1.w);
      d1.x = cvt2(v2.x, v2.y); d1.y = cvt2(v2.z, v2.w);
      d1.z = cvt2(v3.x, v3.y); d1.w = cvt2(v3.z, v3.w);
      *(uint4*)&Wl[o * 32 + swz(o, hf * 2) * 8] = d0;
      *(uint4*)&Wl[o * 32 + swz(o, hf * 2 + 1) * 8] = d1;
      if (SPLIT) {
        uint4 e0, e1;
        e0.x = cvt2lo(v0.x, v0.y, d0.x); e0.y = cvt2lo(v0.z, v0.w, d0.y);
        e0.z = cvt2lo(v1.x, v1.y, d0.z); e0.w = cvt2lo(v1.z, v1.w, d0.w);
        e1.x = cvt2lo(v2.x, v2.y, d1.x); e1.y = cvt2lo(v2.z, v2.w, d1.y);
        e1.z = cvt2lo(v3.x, v3.y, d1.z); e1.w = cvt2lo(v3.z, v3.w, d1.w);
        *(uint4*)&Wl[4096 + o * 32 + swz(o, hf * 2) * 8] = e0;
        *(uint4*)&Wl[4096 + o * 32 + swz(o, hf * 2 + 1) * 8] = e1;
      }
    }
    {
      const int n = tid & 127, ch = (tid >> 7) * 16;
      float val[16];
#pragma unroll
      for (int i = 0; i < 16; ++i) {
        const int cg = cc + ch + i;
        val[i] = tab.p[cg >> 6][tab.bs[cg >> 6] * b + (long long)(cg & 63) * PTS + n0 + n];
      }
      uint4 d0, d1;
      d0.x = cvt2(val[0], val[1]);   d0.y = cvt2(val[2], val[3]);
      d0.z = cvt2(val[4], val[5]);   d0.w = cvt2(val[6], val[7]);
      d1.x = cvt2(val[8], val[9]);   d1.y = cvt2(val[10], val[11]);
      d1.z = cvt2(val[12], val[13]); d1.w = cvt2(val[14], val[15]);
      const int s0 = ch >> 3;
      *(uint4*)&Xl[n * 32 + swz(n, s0) * 8] = d0;
      *(uint4*)&Xl[n * 32 + swz(n, s0 + 1) * 8] = d1;
      if (SPLIT) {
        uint4 e0, e1;
        e0.x = cvt2lo(val[0], val[1], d0.x);   e0.y = cvt2lo(val[2], val[3], d0.y);
        e0.z = cvt2lo(val[4], val[5], d0.z);   e0.w = cvt2lo(val[6], val[7], d0.w);
        e1.x = cvt2lo(val[8], val[9], d1.x);   e1.y = cvt2lo(val[10], val[11], d1.y);
        e1.z = cvt2lo(val[12], val[13], d1.z); e1.w = cvt2lo(val[14], val[15], d1.w);
        *(uint4*)&Xl[4096 + n * 32 + swz(n, s0) * 8] = e0;
        *(uint4*)&Xl[4096 + n * 32 + swz(n, s0 + 1) * 8] = e1;
      }
    }
    __syncthreads();
    bf8 afh[4], bfh[4], afl[4], bfl[4];
#pragma unroll
    for (int mf = 0; mf < 4; ++mf) {
      const int arow = wm * 64 + mf * 16 + (lane & 15);
      const int aoff = arow * 32 + swz(arow, lane >> 4) * 8;
      afh[mf] = *(const bf8*)&Wl[aoff];
      if (SPLIT) afl[mf] = *(const bf8*)&Wl[4096 + aoff];
    }
#pragma unroll
    for (int nf = 0; nf < 4; ++nf) {
      const int brow = wn * 64 + nf * 16 + (lane & 15);
      const int boff = brow * 32 + swz(brow, lane >> 4) * 8;
      bfh[nf] = *(const bf8*)&Xl[boff];
      if (SPLIT) bfl[nf] = *(const bf8*)&Xl[4096 + boff];
    }
#pragma unroll
    for (int mf = 0; mf < 4; ++mf)
#pragma unroll
      for (int nf = 0; nf < 4; ++nf) {
        acc[mf][nf] = __builtin_amdgcn_mfma_f32_16x16x32_bf16(afh[mf], bfh[nf], acc[mf][nf], 0, 0, 0);
        if (SPLIT) {
          acc[mf][nf] = __builtin_amdgcn_mfma_f32_16x16x32_bf16(afl[mf], bfh[nf], acc[mf][nf], 0, 0, 0);
          acc[mf][nf] = __builtin_amdgcn_mfma_f32_16x16x32_bf16(afh[mf], bfl[nf], acc[mf][nf], 0, 0, 0);
        }
      }
  }
  if (MODE == 1) {
#pragma unroll
    for (int mf = 0; mf < 4; ++mf)
#pragma unroll
      for (int r = 0; r < 4; ++r) {
        const int orl = wm * 64 + mf * 16 + (lane >> 4) * 4 + r;
        const int o = o0 + orl;
        const float s = sv[o], bb = bv[o];
        float v = -3.4e38f;
#pragma unroll
        for (int nf = 0; nf < 4; ++nf) v = fmaxf(v, lrelu(fmaf(s, acc[mf][nf][r], bb)));
        v = fmaxf(v, __shfl_xor(v, 1, 64));
        v = fmaxf(v, __shfl_xor(v, 2, 64));
        v = fmaxf(v, __shfl_xor(v, 4, 64));
        v = fmaxf(v, __shfl_xor(v, 8, 64));
        if ((lane & 15) == 0) red[wn][orl] = v;
      }
    __syncthreads();
    if (tid < 128) {
      const float m = fmaxf(red[0][tid], red[1][tid]);
      out[((long long)b * 16 + nt) * 1024 + o0 + tid] = m;
    }
  } else if (MODE == 0) {
#pragma unroll
    for (int mf = 0; mf < 4; ++mf)
#pragma unroll
      for (int r = 0; r < 4; ++r) {
        const int o = o0 + wm * 64 + mf * 16 + (lane >> 4) * 4 + r;
        const float s = sv[o], bb = bv[o];
        const float tv = (tadd != nullptr) ? tadd[(long long)b * O + o] : 0.f;
        float* op = out + ((long long)b * O + o) * PTS + n0 + wn * 64 + (lane & 15);
#pragma unroll
        for (int nf = 0; nf < 4; ++nf)
          op[nf * 16] = lrelu(fmaf(s, acc[mf][nf][r] + tv, bb));
      }
  } else if (MODE == 2) {
#pragma unroll
    for (int mf = 0; mf < 4; ++mf) {
      const int ob = wm * 64 + mf * 16 + (lane >> 4) * 4;
      float s4[4], b4[4];
#pragma unroll
      for (int r = 0; r < 4; ++r) { s4[r] = sv[o0 + ob + r]; b4[r] = bv[o0 + ob + r]; }
#pragma unroll
      for (int nf = 0; nf < 4; ++nf) {
        const int n = n0 + wn * 64 + nf * 16 + (lane & 15);
        float4 v;
        v.x = lrelu(fmaf(s4[0], acc[mf][nf][0], b4[0]));
        v.y = lrelu(fmaf(s4[1], acc[mf][nf][1], b4[1]));
        v.z = lrelu(fmaf(s4[2], acc[mf][nf][2], b4[2]));
        v.w = lrelu(fmaf(s4[3], acc[mf][nf][3], b4[3]));
        *(float4*)&out[((long long)b * PTS + n) * O + o0 + ob] = v;
      }
    }
  } else {  // MODE 3: affine only, f32 [b][PTS][O]
#pragma unroll
    for (int mf = 0; mf < 4; ++mf) {
      const int ob = wm * 64 + mf * 16 + (lane >> 4) * 4;
      float s4[4], b4[4];
#pragma unroll
      for (int r = 0; r < 4; ++r) { s4[r] = sv[o0 + ob + r]; b4[r] = bv[o0 + ob + r]; }
#pragma unroll
      for (int nf = 0; nf < 4; ++nf) {
        const int n = n0 + wn * 64 + nf * 16 + (lane & 15);
        float4 v;
        v.x = fmaf(s4[0], acc[mf][nf][0], b4[0]);
        v.y = fmaf(s4[1], acc[mf][nf][1], b4[1]);
        v.z = fmaf(s4[2], acc[mf][nf][2], b4[2]);
        v.w = fmaf(s4[3], acc[mf][nf][3], b4[3]);
        *(float4*)&out[((long long)b * PTS + n) * O + o0 + ob] = v;
      }
    }
  }
}

// ---------------- tvec (f32 exact; gfin folded: reads gpart) ----------------
__global__ __launch_bounds__(256) void tvec_k(
    const float* __restrict__ cls, const float* __restrict__ wc, const float* __restrict__ sc,
    const float* __restrict__ bc, const float* __restrict__ gp, const float* __restrict__ wf1,
    float* __restrict__ tvec) {
  __shared__ float gs[1024];
  __shared__ float cvs[64];
  const int b = blockIdx.x, tid = threadIdx.x;
  for (int q = tid; q < 1024; q += 256) {
    float m = -3.4e38f;
#pragma unroll 4
    for (int t = 0; t < 16; ++t) m = fmaxf(m, gp[((long long)b * 16 + t) * 1024 + q]);
    gs[q] = m;
  }
  if (tid < 64) {
    float a = 0.f;
#pragma unroll
    for (int j = 0; j < 16; ++j) a = fmaf(wc[tid * 16 + j], cls[b * 16 + j], a);
    cvs[tid] = lrelu(fmaf(sc[tid], a, bc[tid]));
  }
  __syncthreads();
  const float* wr = wf1 + (long long)tid * 1280;
  float a0 = 0.f, a1 = 0.f;
  for (int c = 0; c < 1024; c += 4) {
    const float4 w = *(const float4*)&wr[c];
    const float4 gv = *(const float4*)&gs[c];
    a0 = fmaf(w.x, gv.x, a0); a1 = fmaf(w.y, gv.y, a1);
    a0 = fmaf(w.z, gv.z, a0); a1 = fmaf(w.w, gv.w, a1);
  }
#pragma unroll
  for (int c = 0; c < 64; c += 4) {
    const float4 w = *(const float4*)&wr[1024 + c];
    const float4 cv = *(const float4*)&cvs[c];
    a0 = fmaf(w.x, cv.x, a0); a1 = fmaf(w.y, cv.y, a1);
    a0 = fmaf(w.z, cv.z, a0); a1 = fmaf(w.w, cv.w, a1);
  }
  tvec[b * 256 + tid] = a0 + a1;
}

// ---------------- logits + log_softmax ----------------
__global__ __launch_bounds__(256) void logits_k(const float* __restrict__ f3t, const float* __restrict__ wf4,
                                                float* __restrict__ out) {
  __shared__ float wT[6464];
  const int tid = threadIdx.x, lane = tid & 63, wv = tid >> 6;
  for (int q = tid; q < 6400; q += 256) {
    const int o = q >> 7, c = q & 127;
    wT[c * 50 + o] = wf4[q];
  }
  __syncthreads();
  const long long pn = (long long)blockIdx.x * 4 + wv;
  const float lo = f3t[pn * 128 + lane], hi = f3t[pn * 128 + 64 + lane];
  float a0 = 0.f, a1 = 0.f;
#pragma unroll
  for (int c = 0; c < 64; c += 2) {
    a0 = fmaf(wT[c * 50 + lane], rl(lo, c), a0);
    a1 = fmaf(wT[(c + 1) * 50 + lane], rl(lo, c + 1), a1);
  }
#pragma unroll
  for (int c = 0; c < 64; c += 2) {
    a0 = fmaf(wT[(64 + c) * 50 + lane], rl(hi, c), a0);
    a1 = fmaf(wT[(65 + c) * 50 + lane], rl(hi, c + 1), a1);
  }
  const float logit = (lane < 50) ? (a0 + a1) : -3.4e38f;
  float M = logit;
#pragma unroll
  for (int mask = 1; mask < 64; mask <<= 1) M = fmaxf(M, __shfl_xor(M, mask, 64));
  const float ex = (lane < 50) ? __expf(logit - M) : 0.f;
  float S = ex;
#pragma unroll
  for (int mask = 1; mask < 64; mask <<= 1) S += __shfl_xor(S, mask, 64);
  if (lane < 50) out[pn * 50 + lane] = logit - M - __logf(S);
}

extern "C" void kernel_launch(void* const* d_in, const int* in_sizes, int n_in,
                              void* d_out, int out_size, void* d_ws, size_t ws_size,
                              hipStream_t stream) {
  (void)in_sizes; (void)n_in; (void)out_size; (void)ws_size;
  const float* points = (const float*)d_in[0];
  const float* cls = (const float*)d_in[1];
  const float* w1 = (const float*)d_in[2];
  const float* s1 = (const float*)d_in[3];
  const float* b1 = (const float*)d_in[4];
  const float* w2 = (const float*)d_in[5];
  const float* s2 = (const float*)d_in[6];
  const float* b2 = (const float*)d_in[7];
  const float* w3 = (const float*)d_in[8];
  const float* s3 = (const float*)d_in[9];
  const float* b3 = (const float*)d_in[10];
  const float* w4 = (const float*)d_in[11];
  const float* s4 = (const float*)d_in[12];
  const float* b4 = (const float*)d_in[13];
  const float* w5 = (const float*)d_in[14];
  const float* s5 = (const float*)d_in[15];
  const float* b5 = (const float*)d_in[16];
  const float* w6 = (const float*)d_in[17];
  const float* s6 = (const float*)d_in[18];
  const float* b6 = (const float*)d_in[19];
  const float* wc = (const float*)d_in[20];
  const float* sc = (const float*)d_in[21];
  const float* bc = (const float*)d_in[22];
  const float* wf1 = (const float*)d_in[23];
  const float* sf1 = (const float*)d_in[24];
  const float* bf1 = (const float*)d_in[25];
  const float* wf2 = (const float*)d_in[26];
  const float* sf2 = (const float*)d_in[27];
  const float* bf2 = (const float*)d_in[28];
  const float* wf3 = (const float*)d_in[29];
  const float* sf3 = (const float*)d_in[30];
  const float* bf3 = (const float*)d_in[31];
  const float* wf4 = (const float*)d_in[32];
  float* out = (float*)d_out;
  float* ws = (float*)d_ws;

  // workspace (floats): x1c@0  x2c@2097152  x3c@4194304  f1c@8388608(..16777216)
  // PQf/f3t time-share f1c region; f2c aliases x*c (dead by then); aux @16777216+
  float* x1c = ws;
  float* x2c = ws + 2097152LL;
  float* x3c = ws + 4194304LL;
  float* f1c = ws + 8388608LL;
  float* f2c = ws;
  float* f3t = ws + 8388608LL;
  float* PQf = ws + 8388608LL;
  int* idx = (int*)(ws + 16777216LL);
  float* xxb = ws + 17432576LL;
  float* gpart = ws + 17465344LL;
  float* tvec = ws + 17743872LL;
  float* wc3 = ws + 17747968LL;
  float* sc3 = ws + 17756160LL;
  float* bc3 = ws + 17756288LL;
  float* wc5 = ws + 17756416LL;
  float* sc5 = ws + 17764608LL;
  float* bc5 = ws + 17764736LL;
  unsigned short* W2hi = (unsigned short*)(ws + 17764864LL);
  unsigned short* W2lo = (unsigned short*)(ws + 17766912LL);
  unsigned short* W4hi = (unsigned short*)(ws + 17768960LL);
  unsigned short* W4lo = (unsigned short*)(ws + 17771008LL);

  SrcTab tabX{{x1c, x2c, x3c, nullptr}, {64LL * PTS, 64LL * PTS, 64LL * PTS, 0}};
  SrcTab tabX1{{x1c, nullptr, nullptr, nullptr}, {64LL * PTS, 0, 0, 0}};
  SrcTab tabX2{{x2c, nullptr, nullptr, nullptr}, {64LL * PTS, 0, 0, 0}};
  SrcTab tabF1{{f1c, f1c + 64 * PTS, f1c + 128 * PTS, f1c + 192 * PTS},
               {256LL * PTS, 256LL * PTS, 256LL * PTS, 256LL * PTS}};
  SrcTab tabF2{{f2c, f2c + 64 * PTS, f2c + 128 * PTS, f2c + 192 * PTS},
               {256LL * PTS, 256LL * PTS, 256LL * PTS, 256LL * PTS}};

  prep_k<<<64, 256, 0, stream>>>(w3, s3, b3, w5, s5, b5, wc3, sc3, bc3, wc5, sc5, bc5);
  wsplit_k<<<32, 256, 0, stream>>>(w2, w4, W2hi, W2lo, W4hi, W4lo);

  // ---- kNN 1 (fused, f32 bitwise-exact) + edge1 (split-MFMA) ----
  xnorm_k<3><<<128, 256, 0, stream>>>(points, xxb);
  fknn3_k<3><<<dim3(512, 16), 256, 0, stream>>>(points, xxb, idx);
  pq1_k<<<8192, 256, 0, stream>>>(points, w1, s1, b1, PQf);
  edgemf_k<<<4096, 256, 0, stream>>>(PQf, idx, W2hi, W2lo, s2, b2, x1c);

  // ---- kNN 2 + edge2 (split-MFMA) ----
  xnorm_k<64><<<128, 256, 0, stream>>>(x1c, xxb);
  fknn3_k<64><<<dim3(512, 16), 256, 0, stream>>>(x1c, xxb, idx);
  mfgemm_k<3, 1><<<dim3(16, 1, 16), 256, 0, stream>>>(wc3, 64, 0, tabX1, 64, sc3, bc3, nullptr, PQf, 128);
  edgemf_k<<<4096, 256, 0, stream>>>(PQf, idx, W4hi, W4lo, s4, b4, x2c);

  // ---- kNN 3 + edge3 ----
  xnorm_k<64><<<128, 256, 0, stream>>>(x2c, xxb);
  fknn3_k<64><<<dim3(512, 16), 256, 0, stream>>>(x2c, xxb, idx);
  mfgemm_k<3, 1><<<dim3(16, 1, 16), 256, 0, stream>>>(wc5, 64, 0, tabX2, 64, sc5, bc5, nullptr, PQf, 128);
  edge3f_k<<<1024, 256, 0, stream>>>(PQf, idx, x3c);

  // ---- head (split-MFMA) ----
  mfgemm_k<1, 1><<<dim3(16, 8, 16), 256, 0, stream>>>(w6, 192, 0, tabX, 192, s6, b6, nullptr, gpart, 1024);
  tvec_k<<<16, 256, 0, stream>>>(cls, wc, sc, bc, gpart, wf1, tvec);
  mfgemm_k<0, 1><<<dim3(16, 2, 16), 256, 0, stream>>>(wf1, 1280, 1088, tabX, 192, sf1, bf1, tvec, f1c, 256);
  mfgemm_k<0, 1><<<dim3(16, 2, 16), 256, 0, stream>>>(wf2, 256, 0, tabF1, 256, sf2, bf2, nullptr, f2c, 256);
  mfgemm_k<2, 1><<<dim3(16, 1, 16), 256, 0, stream>>>(wf3, 256, 0, tabF2, 256, sf3, bf3, nullptr, f3t, 128);
  logits_k<<<8192, 256, 0, stream>>>(f3t, wf4, out);
}

// Round 11
// 1059.629 us; speedup vs baseline: 6.0395x; 1.1547x over previous
//
#include <hip/hip_runtime.h>

constexpr int PTS = 2048;   // points per batch
constexpr int KK  = 20;     // knn

typedef __attribute__((ext_vector_type(8))) short bf8;
typedef __attribute__((ext_vector_type(4))) float f32x4;

static __device__ __forceinline__ float lrelu(float x) { return fmaxf(x, 0.2f * x); }
static __device__ __forceinline__ float rl(float v, int l) {
  return __int_as_float(__builtin_amdgcn_readlane(__float_as_int(v), l));
}
static __device__ __forceinline__ unsigned cvt2(float lo, float hi) {
  unsigned r;
  asm("v_cvt_pk_bf16_f32 %0, %1, %2" : "=v"(r) : "v"(lo), "v"(hi));
  return r;
}
// residual after bf16-hi extraction: packs bf16(a - hi(a)), bf16(b - hi(b))
static __device__ __forceinline__ unsigned cvt2lo(float a, float b, unsigned h) {
  return cvt2(a - __uint_as_float(h << 16), b - __uint_as_float(h & 0xffff0000u));
}
static __device__ __forceinline__ unsigned short rne_bf16(float v) {
  unsigned u = __float_as_uint(v);
  return (unsigned short)((u + 0x7fffu + ((u >> 16) & 1u)) >> 16);
}
static __device__ __forceinline__ float bf2f(unsigned short u) {
  return __uint_as_float(((unsigned)u) << 16);
}
static __device__ __forceinline__ int swz(int row, int slot) {
  return slot ^ (row & 3) ^ ((row >> 2) & 3);   // 16B-slot swizzle, conflict-free
}
static __device__ __forceinline__ void argmax64(float& v, int& m) {
#pragma unroll
  for (int mask = 1; mask < 64; mask <<= 1) {
    float ov = __shfl_xor(v, mask, 64);
    int om = __shfl_xor(m, mask, 64);
    if (ov > v || (ov == v && om < m)) { v = ov; m = om; }
  }
}

// ---------------- xx[b][m] = sum_c x[c][m]^2 ----------------
template <int C>
__global__ __launch_bounds__(256) void xnorm_k(const float* __restrict__ x, float* __restrict__ xx) {
  const int i = blockIdx.x * 256 + threadIdx.x;
  const int b = i >> 11, m = i & 2047;
  float s = 0.f;
#pragma unroll
  for (int c = 0; c < C; ++c) {
    const float v = x[((long long)b * C + c) * PTS + m];
    s = fmaf(v, v, s);
  }
  xx[i] = s;
}

// ---------------- fused kNN v4: dist into LDS + lazy top-3 prefetch selection ----------------
// Block: 256 thr / 4 waves / 4 points. Wave w owns m-tiles {2w, 2w+1} for ALL 4 points.
// Distance = 2*sum_c xn*xm - xx[m], same fmaf chain order (bitwise identical to prior rounds).
// Selection: lane prefetches local top-3 (named scalars); per round just argmax64 + owner shift.
// Tree re-runs only when a lane wins a 3rd+ time (wave-uniform branch, rare).
// Invariant: c1 >= c2 >= c3 >= all remaining d-regs; consumed/prefetched slots are NEG in d-regs.
// m encode: m = (s>>2)*256 + 4*lane + (s&3); ascending s = ascending m (ties: lower s wins).
template <int C>
__global__ __launch_bounds__(256, 4) void fknn4_k(const float* __restrict__ x, const float* __restrict__ xx,
                                                  int* __restrict__ idxout) {
  __shared__ float dist[4][2112];
  __shared__ float xns[4][68];
  const int tid = threadIdx.x, lane = tid & 63, wid = tid >> 6;
  const int b = blockIdx.y;
  const int n0 = blockIdx.x * 4;

  if (tid < 4 * C) {
    const int p = tid & 3, c = tid >> 2;
    xns[p][c] = x[((long long)b * C + c) * PTS + n0 + p];
  }
  __syncthreads();

  float acc[4][2][4] = {};  // [point][tt][i] — static indices only
  const float* px0 = x + (long long)b * C * PTS + (2 * wid) * 256 + 4 * lane;
  const float* px1 = px0 + 256;
#pragma unroll 4
  for (int c = 0; c < C; ++c) {
    const f32x4 v0 = *(const f32x4*)(px0 + (long long)c * PTS);
    const f32x4 v1 = *(const f32x4*)(px1 + (long long)c * PTS);
    const float xn0 = xns[0][c], xn1 = xns[1][c], xn2 = xns[2][c], xn3 = xns[3][c];
#pragma unroll
    for (int i = 0; i < 4; ++i) {
      acc[0][0][i] = fmaf(xn0, v0[i], acc[0][0][i]);
      acc[1][0][i] = fmaf(xn1, v0[i], acc[1][0][i]);
      acc[2][0][i] = fmaf(xn2, v0[i], acc[2][0][i]);
      acc[3][0][i] = fmaf(xn3, v0[i], acc[3][0][i]);
      acc[0][1][i] = fmaf(xn0, v1[i], acc[0][1][i]);
      acc[1][1][i] = fmaf(xn1, v1[i], acc[1][1][i]);
      acc[2][1][i] = fmaf(xn2, v1[i], acc[2][1][i]);
      acc[3][1][i] = fmaf(xn3, v1[i], acc[3][1][i]);
    }
  }
#pragma unroll
  for (int tt = 0; tt < 2; ++tt) {
    const f32x4 xv = *(const f32x4*)&xx[b * 2048 + (2 * wid + tt) * 256 + 4 * lane];
#pragma unroll
    for (int p = 0; p < 4; ++p)
#pragma unroll
      for (int i = 0; i < 4; ++i)
        dist[p][lane * 33 + 8 * wid + 4 * tt + i] = 2.f * acc[p][tt][i] - xv[i];
  }
  __syncthreads();

  // ---- selection: wave w -> point n0+w ----
  const float NEG = -3.4e38f;
  float* dp = dist[wid];
  const int n = n0 + wid;
#define LDD(r) float d##r = dp[lane * 33 + r];
  LDD(0) LDD(1) LDD(2) LDD(3) LDD(4) LDD(5) LDD(6) LDD(7)
  LDD(8) LDD(9) LDD(10) LDD(11) LDD(12) LDD(13) LDD(14) LDD(15)
  LDD(16) LDD(17) LDD(18) LDD(19) LDD(20) LDD(21) LDD(22) LDD(23)
  LDD(24) LDD(25) LDD(26) LDD(27) LDD(28) LDD(29) LDD(30) LDD(31)
#undef LDD

#define P2(vA, iA, vB, iB, vO, iO) float vO = vA; int iO = iA; if (vB > vA) { vO = vB; iO = iB; }
#define TREE32(bvout, bsout)                                                            \
  {                                                                                     \
    P2(d0, 0, d1, 1, e0, j0) P2(d2, 2, d3, 3, e1, j1) P2(d4, 4, d5, 5, e2, j2)          \
    P2(d6, 6, d7, 7, e3, j3) P2(d8, 8, d9, 9, e4, j4) P2(d10, 10, d11, 11, e5, j5)      \
    P2(d12, 12, d13, 13, e6, j6) P2(d14, 14, d15, 15, e7, j7)                           \
    P2(d16, 16, d17, 17, e8, j8) P2(d18, 18, d19, 19, e9, j9)                           \
    P2(d20, 20, d21, 21, e10, j10) P2(d22, 22, d23, 23, e11, j11)                       \
    P2(d24, 24, d25, 25, e12, j12) P2(d26, 26, d27, 27, e13, j13)                       \
    P2(d28, 28, d29, 29, e14, j14) P2(d30, 30, d31, 31, e15, j15)                       \
    P2(e0, j0, e1, j1, f0, k0) P2(e2, j2, e3, j3, f1, k1)                               \
    P2(e4, j4, e5, j5, f2, k2) P2(e6, j6, e7, j7, f3, k3)                               \
    P2(e8, j8, e9, j9, f4, k4) P2(e10, j10, e11, j11, f5, k5)                           \
    P2(e12, j12, e13, j13, f6, k6) P2(e14, j14, e15, j15, f7, k7)                       \
    P2(f0, k0, f1, k1, g0, l0) P2(f2, k2, f3, k3, g1, l1)                               \
    P2(f4, k4, f5, k5, g2, l2) P2(f6, k6, f7, k7, g3, l3)                               \
    P2(g0, l0, g1, l1, h0, q0) P2(g2, l2, g3, l3, h1, q1)                               \
    P2(h0, q0, h1, q1, tf, ti)                                                          \
    bvout = tf;                                                                         \
    bsout = ti;                                                                         \
  }

  float c1v, c2v, c3v;
  int c1s, c2s, c3s;
  TREE32(c1v, c1s)
#define INVR(r) d##r = (c1s == r) ? NEG : d##r;
  INVR(0) INVR(1) INVR(2) INVR(3) INVR(4) INVR(5) INVR(6) INVR(7)
  INVR(8) INVR(9) INVR(10) INVR(11) INVR(12) INVR(13) INVR(14) INVR(15)
  INVR(16) INVR(17) INVR(18) INVR(19) INVR(20) INVR(21) INVR(22) INVR(23)
  INVR(24) INVR(25) INVR(26) INVR(27) INVR(28) INVR(29) INVR(30) INVR(31)
#undef INVR
  TREE32(c2v, c2s)
#define INVR(r) d##r = (c2s == r) ? NEG : d##r;
  INVR(0) INVR(1) INVR(2) INVR(3) INVR(4) INVR(5) INVR(6) INVR(7)
  INVR(8) INVR(9) INVR(10) INVR(11) INVR(12) INVR(13) INVR(14) INVR(15)
  INVR(16) INVR(17) INVR(18) INVR(19) INVR(20) INVR(21) INVR(22) INVR(23)
  INVR(24) INVR(25) INVR(26) INVR(27) INVR(28) INVR(29) INVR(30) INVR(31)
#undef INVR
  TREE32(c3v, c3s)
#define INVR(r) d##r = (c3s == r) ? NEG : d##r;
  INVR(0) INVR(1) INVR(2) INVR(3) INVR(4) INVR(5) INVR(6) INVR(7)
  INVR(8) INVR(9) INVR(10) INVR(11) INVR(12) INVR(13) INVR(14) INVR(15)
  INVR(16) INVR(17) INVR(18) INVR(19) INVR(20) INVR(21) INVR(22) INVR(23)
  INVR(24) INVR(25) INVR(26) INVR(27) INVR(28) INVR(29) INVR(30) INVR(31)
#undef INVR
  int c1m = ((c1s >> 2) << 8) + 4 * lane + (c1s & 3);
  int c2m = ((c2s >> 2) << 8) + 4 * lane + (c2s & 3);
  int c3m = ((c3s >> 2) << 8) + 4 * lane + (c3s & 3);

  int keep = 0;
  for (int rd = 0; rd < KK; ++rd) {
    float cv = c1v; int cm = c1m;
    argmax64(cv, cm);
    if (lane == rd) keep = cm;
    const int ol = (cm >> 2) & 63;            // owner lane (wave-uniform)
    const bool own = (lane == ol);
    if (own) { c1v = c2v; c1m = c2m; c2v = c3v; c2m = c3m; c3v = NEG; }
    const float oc1 = __shfl(c1v, ol, 64);    // owner's new candidate (uniform value)
    if (oc1 == NEG) {                         // uniform branch: owner exhausted prefetch
      float nv; int ns;
      TREE32(nv, ns)
      const int nm = ((ns >> 2) << 8) + 4 * lane + (ns & 3);
      if (own) { c1v = nv; c1m = nm; }
#define INVO(r) d##r = (own && ns == r) ? NEG : d##r;
      INVO(0) INVO(1) INVO(2) INVO(3) INVO(4) INVO(5) INVO(6) INVO(7)
      INVO(8) INVO(9) INVO(10) INVO(11) INVO(12) INVO(13) INVO(14) INVO(15)
      INVO(16) INVO(17) INVO(18) INVO(19) INVO(20) INVO(21) INVO(22) INVO(23)
      INVO(24) INVO(25) INVO(26) INVO(27) INVO(28) INVO(29) INVO(30) INVO(31)
#undef INVO
    }
  }
#undef TREE32
#undef P2
  if (lane < KK) idxout[((long long)b * PTS + n) * KK + lane] = keep;
}

// ---------------- prep: combined PQ weights (f32) for edge2/edge3 ----------------
__global__ __launch_bounds__(256) void prep_k(
    const float* __restrict__ w3, const float* __restrict__ s3, const float* __restrict__ b3,
    const float* __restrict__ w5, const float* __restrict__ s5, const float* __restrict__ b5,
    float* __restrict__ wc3, float* __restrict__ sc3, float* __restrict__ bc3,
    float* __restrict__ wc5, float* __restrict__ sc5, float* __restrict__ bc5) {
  const int i = blockIdx.x * 256 + threadIdx.x;  // 16384
  const int half = i >> 13;
  const int r = i & 8191;
  const float* w = half ? w5 : w3;
  float* wcp = half ? wc5 : wc3;
  const int o = r >> 6, c = r & 63;
  wcp[r] = (o < 64) ? w[o * 128 + c] : (w[(o - 64) * 128 + 64 + c] - w[(o - 64) * 128 + c]);
  if (r < 128) {
    const float* s = half ? s5 : s3;
    const float* bb = half ? b5 : b3;
    float* scp = half ? sc5 : sc3;
    float* bcp = half ? bc5 : bc3;
    scp[r] = s[r & 63];
    bcp[r] = (r < 64) ? 0.f : bb[r - 64];
  }
}

// ---------------- split conv2 weights to bf16 hi/lo ----------------
__global__ __launch_bounds__(256) void wsplit_k(const float* __restrict__ w2, const float* __restrict__ w4,
                                                unsigned short* __restrict__ W2hi, unsigned short* __restrict__ W2lo,
                                                unsigned short* __restrict__ W4hi, unsigned short* __restrict__ W4lo) {
  const int i = blockIdx.x * 256 + threadIdx.x;  // 8192
  const float v = (i < 4096) ? w2[i] : w4[i - 4096];
  const unsigned short h = rne_bf16(v);
  const unsigned short l = rne_bf16(v - bf2f(h));
  if (i < 4096) { W2hi[i] = h; W2lo[i] = l; }
  else { W4hi[i - 4096] = h; W4lo[i - 4096] = l; }
}

// ---------------- PQ for edge1 (f32 out, [b][n][128]: P=0..63, Q=64..127) ----------------
__global__ __launch_bounds__(256) void pq1_k(const float* __restrict__ pts,
    const float* __restrict__ w1, const float* __restrict__ s1, const float* __restrict__ b1,
    float* __restrict__ PQ) {
  const int i = blockIdx.x * 256 + threadIdx.x;  // 16*2048*64
  const int o = i & 63;
  const int bn = i >> 6;
  const int b = bn >> 11, n = bn & 2047;
  const float* pb = pts + (long long)b * 3 * PTS;
  const float x = pb[n], y = pb[PTS + n], z = pb[2 * PTS + n];
  const float s = s1[o];
  const float wa0 = w1[o * 6], wa1 = w1[o * 6 + 1], wa2 = w1[o * 6 + 2];
  const float wb0 = w1[o * 6 + 3], wb1 = w1[o * 6 + 4], wb2 = w1[o * 6 + 5];
  PQ[(long long)bn * 128 + o] = s * (wa0 * x + wa1 * y + wa2 * z);
  PQ[(long long)bn * 128 + 64 + o] =
      fmaf(s, (wb0 - wa0) * x + (wb1 - wa1) * y + (wb2 - wa2) * z, b1[o]);
}

// ---------------- MFMA EdgeConv (split-bf16 3-pass): conv2 as pair-GEMM, max over k ----------------
static __device__ __forceinline__ void mkfrag2(const float4 p0, const float4 p1,
                                               const float4 q0, const float4 q1,
                                               bf8& hi, bf8& lo) {
  const float y[8] = {p0.x + q0.x, p0.y + q0.y, p0.z + q0.z, p0.w + q0.w,
                      p1.x + q1.x, p1.y + q1.y, p1.z + q1.z, p1.w + q1.w};
  union { unsigned u[4]; bf8 v; } rh, rlo;
#pragma unroll
  for (int i = 0; i < 4; ++i) {
    const float a = lrelu(y[2 * i]), b = lrelu(y[2 * i + 1]);
    const unsigned h = cvt2(a, b);
    rh.u[i] = h;
    rlo.u[i] = cvt2lo(a, b, h);
  }
  hi = rh.v; lo = rlo.v;
}

__global__ __launch_bounds__(256) void edgemf_k(
    const float* __restrict__ PQ, const int* __restrict__ idxb,
    const unsigned short* __restrict__ Whi, const unsigned short* __restrict__ Wlo,
    const float* __restrict__ s2v, const float* __restrict__ b2v,
    float* __restrict__ outC) {
  const int lane = threadIdx.x & 63, wid = threadIdx.x >> 6;
  const int g = blockIdx.x;                 // 16b * 256
  const int b = g >> 8;
  const int n0 = (g & 255) * 8 + wid * 2;   // 8 pts/block, 2 per wave
  bf8 wbh[4][2], wbl[4][2];
#pragma unroll
  for (int nf = 0; nf < 4; ++nf)
#pragma unroll
    for (int kt = 0; kt < 2; ++kt) {
      const int off = (16 * nf + (lane & 15)) * 64 + kt * 32 + (lane >> 4) * 8;
      wbh[nf][kt] = *(const bf8*)&Whi[off];
      wbl[nf][kt] = *(const bf8*)&Wlo[off];
    }
  const float* Pb = PQ + (long long)b * PTS * 128;
  const int co = (lane >> 4) * 8;
  int mm[2][2];
  float4 qa[2][2], qb[2][2];
#pragma unroll
  for (int pt = 0; pt < 2; ++pt) {
    const int n = n0 + pt;
    const int* ir = idxb + ((long long)b * PTS + n) * KK;
    const int j1 = 16 + (lane & 15);
    mm[pt][0] = ir[lane & 15];
    mm[pt][1] = ir[j1 < KK ? j1 : 0];
    qa[pt][0] = *(const float4*)&Pb[n * 128 + 64 + co];
    qb[pt][0] = *(const float4*)&Pb[n * 128 + 68 + co];
    qa[pt][1] = *(const float4*)&Pb[n * 128 + 96 + co];
    qb[pt][1] = *(const float4*)&Pb[n * 128 + 100 + co];
  }
  f32x4 acc[4][4] = {};
#pragma unroll
  for (int pt = 0; pt < 2; ++pt) {
#pragma unroll
    for (int f = 0; f < 2; ++f) {
      const int m = mm[pt][f];
      const float4 p0a = *(const float4*)&Pb[m * 128 + co];
      const float4 p0b = *(const float4*)&Pb[m * 128 + 4 + co];
      const float4 p1a = *(const float4*)&Pb[m * 128 + 32 + co];
      const float4 p1b = *(const float4*)&Pb[m * 128 + 36 + co];
      bf8 a0h, a0l, a1h, a1l;
      mkfrag2(p0a, p0b, qa[pt][0], qb[pt][0], a0h, a0l);
      mkfrag2(p1a, p1b, qa[pt][1], qb[pt][1], a1h, a1l);
      const int mf = pt * 2 + f;
#pragma unroll
      for (int nf = 0; nf < 4; ++nf) {
        acc[mf][nf] = __builtin_amdgcn_mfma_f32_16x16x32_bf16(a0h, wbh[nf][0], acc[mf][nf], 0, 0, 0);
        acc[mf][nf] = __builtin_amdgcn_mfma_f32_16x16x32_bf16(a0l, wbh[nf][0], acc[mf][nf], 0, 0, 0);
        acc[mf][nf] = __builtin_amdgcn_mfma_f32_16x16x32_bf16(a0h, wbl[nf][0], acc[mf][nf], 0, 0, 0);
      }
#pragma unroll
      for (int nf = 0; nf < 4; ++nf) {
        acc[mf][nf] = __builtin_amdgcn_mfma_f32_16x16x32_bf16(a1h, wbh[nf][1], acc[mf][nf], 0, 0, 0);
        acc[mf][nf] = __builtin_amdgcn_mfma_f32_16x16x32_bf16(a1l, wbh[nf][1], acc[mf][nf], 0, 0, 0);
        acc[mf][nf] = __builtin_amdgcn_mfma_f32_16x16x32_bf16(a1h, wbl[nf][1], acc[mf][nf], 0, 0, 0);
      }
    }
  }
#pragma unroll
  for (int nf = 0; nf < 4; ++nf) {
    const int o = 16 * nf + (lane & 15);
    const float so = s2v[o], bo = b2v[o];
#pragma unroll
    for (int pt = 0; pt < 2; ++pt) {
      float v = -3.4e38f;
#pragma unroll
      for (int f = 0; f < 2; ++f) {
        const int mf = pt * 2 + f;
#pragma unroll
        for (int r = 0; r < 4; ++r) v = fmaxf(v, lrelu(fmaf(so, acc[mf][nf][r], bo)));
      }
      v = fmaxf(v, __shfl_xor(v, 16, 64));
      v = fmaxf(v, __shfl_xor(v, 32, 64));
      if ((lane >> 4) == 0) outC[((long long)b * 64 + o) * PTS + n0 + pt] = v;
    }
  }
}

// ---------------- edge3: gather-max of lrelu(P+Q), f32 PQ ----------------
__global__ __launch_bounds__(256) void edge3f_k(const float* __restrict__ PQ,
                                                const int* __restrict__ idxb, float* __restrict__ outC) {
  const int lane = threadIdx.x & 63, wid = threadIdx.x >> 6;
  const int g = blockIdx.x;
  const int b = g >> 6, n0 = ((g & 63) << 5) + (wid << 3);
  const float* Pb = PQ + (long long)b * PTS * 128;
  for (int pt = 0; pt < 8; ++pt) {
    const int n = n0 + pt;
    const float qv = Pb[n * 128 + 64 + lane];
    const int* ir = idxb + ((long long)b * PTS + n) * KK;
    float gm = -3.4e38f;
#pragma unroll 4
    for (int j = 0; j < KK; ++j) {
      const int m = ir[j];
      gm = fmaxf(gm, lrelu(Pb[m * 128 + lane] + qv));
    }
    outC[((long long)b * 64 + lane) * PTS + n] = gm;
  }
}

// ---------------- bf16 MFMA GEMM, optional split-bf16 3-pass ----------------
// MODE 0: affine+lrelu -> [b][O][PTS] (+tadd) | MODE 1: affine+lrelu, max over n -> gpart
// MODE 2: affine+lrelu -> [b][PTS][O] f32     | MODE 3: affine only -> f32 [b][PTS][O]
struct SrcTab { const float* p[4]; long long bs[4]; };

template <int MODE, int SPLIT>
__global__ __launch_bounds__(256) void mfgemm_k(
    const float* __restrict__ W, int wstride, int c0, SrcTab tab, int C,
    const float* __restrict__ sv, const float* __restrict__ bv, const float* __restrict__ tadd,
    float* __restrict__ out, int O) {
  __shared__ __align__(16) short Wl[(1 + SPLIT) * 128 * 32];
  __shared__ __align__(16) short Xl[(1 + SPLIT) * 128 * 32];
  __shared__ float red[2][128];
  const int tid = threadIdx.x, lane = tid & 63, wid = tid >> 6;
  const int nt = blockIdx.x, ot = blockIdx.y, b = blockIdx.z;
  const int n0 = nt * 128, o0 = ot * 128;
  const int wm = wid >> 1, wn = wid & 1;
  f32x4 acc[4][4] = {};
  for (int cc = 0; cc < C; cc += 32) {
    __syncthreads();
    {
      const int o = tid >> 1, hf = tid & 1;
      const float* src = &W[(long long)(o0 + o) * wstride + c0 + cc + hf * 16];
      const float4 v0 = *(const float4*)src;
      const float4 v1 = *(const float4*)(src + 4);
      const float4 v2 = *(const float4*)(src + 8);
      const float4 v3 = *(const float4*)(src + 12);
      uint4 d0, d1;
      d0.x = cvt2(v0.x, v0.y); d0.y = cvt2(v0.z, v0.w);
      d0.z = cvt2(v1.x, v1.y); d0.w = cvt2(v1.z, v1.w);
      d1.x = cvt2(v2.x, v2.y); d1.y = cvt2(v2.z, v2.w);
      d1.z = cvt2(v3.x, v3.y); d1.w = cvt2(v3.z, v3.w);
      *(uint4*)&Wl[o * 32 + swz(o, hf * 2) * 8] = d0;
      *(uint4*)&Wl[o * 32 + swz(o, hf * 2 + 1) * 8] = d1;
      if (SPLIT) {
        uint4 e0, e1;
        e0.x = cvt2lo(v0.x, v0.y, d0.x); e0.y = cvt2lo(v0.z, v0.w, d0.y);
        e0.z = cvt2lo(v1.x, v1.y, d0.z); e0.w = cvt2lo(v1.z, v1.w, d0.w);
        e1.x = cvt2lo(v2.x, v2.y, d1.x); e1.y = cvt2lo(v2.z, v2.w, d1.y);
        e1.z = cvt2lo(v3.x, v3.y, d1.z); e1.w = cvt2lo(v3.z, v3.w, d1.w);
        *(uint4*)&Wl[4096 + o * 32 + swz(o, hf * 2) * 8] = e0;
        *(uint4*)&Wl[4096 + o * 32 + swz(o, hf * 2 + 1) * 8] = e1;
      }
    }
    {
      const int n = tid & 127, ch = (tid >> 7) * 16;
      float val[16];
#pragma unroll
      for (int i = 0; i < 16; ++i) {
        const int cg = cc + ch + i;
        val[i] = tab.p[cg >> 6][tab.bs[cg >> 6] * b + (long long)(cg & 63) * PTS + n0 + n];
      }
      uint4 d0, d1;
      d0.x = cvt2(val[0], val[1]);   d0.y = cvt2(val[2], val[3]);
      d0.z = cvt2(val[4], val[5]);   d0.w = cvt2(val[6], val[7]);
      d1.x = cvt2(val[8], val[9]);   d1.y = cvt2(val[10], val[11]);
      d1.z = cvt2(val[12], val[13]); d1.w = cvt2(val[14], val[15]);
      const int s0 = ch >> 3;
      *(uint4*)&Xl[n * 32 + swz(n, s0) * 8] = d0;
      *(uint4*)&Xl[n * 32 + swz(n, s0 + 1) * 8] = d1;
      if (SPLIT) {
        uint4 e0, e1;
        e0.x = cvt2lo(val[0], val[1], d0.x);   e0.y = cvt2lo(val[2], val[3], d0.y);
        e0.z = cvt2lo(val[4], val[5], d0.z);   e0.w = cvt2lo(val[6], val[7], d0.w);
        e1.x = cvt2lo(val[8], val[9], d1.x);   e1.y = cvt2lo(val[10], val[11], d1.y);
        e1.z = cvt2lo(val[12], val[13], d1.z); e1.w = cvt2lo(val[14], val[15], d1.w);
        *(uint4*)&Xl[4096 + n * 32 + swz(n, s0) * 8] = e0;
        *(uint4*)&Xl[4096 + n * 32 + swz(n, s0 + 1) * 8] = e1;
      }
    }
    __syncthreads();
    bf8 afh[4], bfh[4], afl[4], bfl[4];
#pragma unroll
    for (int mf = 0; mf < 4; ++mf) {
      const int arow = wm * 64 + mf * 16 + (lane & 15);
      const int aoff = arow * 32 + swz(arow, lane >> 4) * 8;
      afh[mf] = *(const bf8*)&Wl[aoff];
      if (SPLIT) afl[mf] = *(const bf8*)&Wl[4096 + aoff];
    }
#pragma unroll
    for (int nf = 0; nf < 4; ++nf) {
      const int brow = wn * 64 + nf * 16 + (lane & 15);
      const int boff = brow * 32 + swz(brow, lane >> 4) * 8;
      bfh[nf] = *(const bf8*)&Xl[boff];
      if (SPLIT) bfl[nf] = *(const bf8*)&Xl[4096 + boff];
    }
#pragma unroll
    for (int mf = 0; mf < 4; ++mf)
#pragma unroll
      for (int nf = 0; nf < 4; ++nf) {
        acc[mf][nf] = __builtin_amdgcn_mfma_f32_16x16x32_bf16(afh[mf], bfh[nf], acc[mf][nf], 0, 0, 0);
        if (SPLIT) {
          acc[mf][nf] = __builtin_amdgcn_mfma_f32_16x16x32_bf16(afl[mf], bfh[nf], acc[mf][nf], 0, 0, 0);
          acc[mf][nf] = __builtin_amdgcn_mfma_f32_16x16x32_bf16(afh[mf], bfl[nf], acc[mf][nf], 0, 0, 0);
        }
      }
  }
  if (MODE == 1) {
#pragma unroll
    for (int mf = 0; mf < 4; ++mf)
#pragma unroll
      for (int r = 0; r < 4; ++r) {
        const int orl = wm * 64 + mf * 16 + (lane >> 4) * 4 + r;
        const int o = o0 + orl;
        const float s = sv[o], bb = bv[o];
        float v = -3.4e38f;
#pragma unroll
        for (int nf = 0; nf < 4; ++nf) v = fmaxf(v, lrelu(fmaf(s, acc[mf][nf][r], bb)));
        v = fmaxf(v, __shfl_xor(v, 1, 64));
        v = fmaxf(v, __shfl_xor(v, 2, 64));
        v = fmaxf(v, __shfl_xor(v, 4, 64));
        v = fmaxf(v, __shfl_xor(v, 8, 64));
        if ((lane & 15) == 0) red[wn][orl] = v;
      }
    __syncthreads();
    if (tid < 128) {
      const float m = fmaxf(red[0][tid], red[1][tid]);
      out[((long long)b * 16 + nt) * 1024 + o0 + tid] = m;
    }
  } else if (MODE == 0) {
#pragma unroll
    for (int mf = 0; mf < 4; ++mf)
#pragma unroll
      for (int r = 0; r < 4; ++r) {
        const int o = o0 + wm * 64 + mf * 16 + (lane >> 4) * 4 + r;
        const float s = sv[o], bb = bv[o];
        const float tv = (tadd != nullptr) ? tadd[(long long)b * O + o] : 0.f;
        float* op = out + ((long long)b * O + o) * PTS + n0 + wn * 64 + (lane & 15);
#pragma unroll
        for (int nf = 0; nf < 4; ++nf)
          op[nf * 16] = lrelu(fmaf(s, acc[mf][nf][r] + tv, bb));
      }
  } else if (MODE == 2) {
#pragma unroll
    for (int mf = 0; mf < 4; ++mf) {
      const int ob = wm * 64 + mf * 16 + (lane >> 4) * 4;
      float s4[4], b4[4];
#pragma unroll
      for (int r = 0; r < 4; ++r) { s4[r] = sv[o0 + ob + r]; b4[r] = bv[o0 + ob + r]; }
#pragma unroll
      for (int nf = 0; nf < 4; ++nf) {
        const int n = n0 + wn * 64 + nf * 16 + (lane & 15);
        float4 v;
        v.x = lrelu(fmaf(s4[0], acc[mf][nf][0], b4[0]));
        v.y = lrelu(fmaf(s4[1], acc[mf][nf][1], b4[1]));
        v.z = lrelu(fmaf(s4[2], acc[mf][nf][2], b4[2]));
        v.w = lrelu(fmaf(s4[3], acc[mf][nf][3], b4[3]));
        *(float4*)&out[((long long)b * PTS + n) * O + o0 + ob] = v;
      }
    }
  } else {  // MODE 3: affine only, f32 [b][PTS][O]
#pragma unroll
    for (int mf = 0; mf < 4; ++mf) {
      const int ob = wm * 64 + mf * 16 + (lane >> 4) * 4;
      float s4[4], b4[4];
#pragma unroll
      for (int r = 0; r < 4; ++r) { s4[r] = sv[o0 + ob + r]; b4[r] = bv[o0 + ob + r]; }
#pragma unroll
      for (int nf = 0; nf < 4; ++nf) {
        const int n = n0 + wn * 64 + nf * 16 + (lane & 15);
        float4 v;
        v.x = fmaf(s4[0], acc[mf][nf][0], b4[0]);
        v.y = fmaf(s4[1], acc[mf][nf][1], b4[1]);
        v.z = fmaf(s4[2], acc[mf][nf][2], b4[2]);
        v.w = fmaf(s4[3], acc[mf][nf][3], b4[3]);
        *(float4*)&out[((long long)b * PTS + n) * O + o0 + ob] = v;
      }
    }
  }
}

// ---------------- tvec (f32 exact; gfin folded: reads gpart) ----------------
__global__ __launch_bounds__(256) void tvec_k(
    const float* __restrict__ cls, const float* __restrict__ wc, const float* __restrict__ sc,
    const float* __restrict__ bc, const float* __restrict__ gp, const float* __restrict__ wf1,
    float* __restrict__ tvec) {
  __shared__ float gs[1024];
  __shared__ float cvs[64];
  const int b = blockIdx.x, tid = threadIdx.x;
  for (int q = tid; q < 1024; q += 256) {
    float m = -3.4e38f;
#pragma unroll 4
    for (int t = 0; t < 16; ++t) m = fmaxf(m, gp[((long long)b * 16 + t) * 1024 + q]);
    gs[q] = m;
  }
  if (tid < 64) {
    float a = 0.f;
#pragma unroll
    for (int j = 0; j < 16; ++j) a = fmaf(wc[tid * 16 + j], cls[b * 16 + j], a);
    cvs[tid] = lrelu(fmaf(sc[tid], a, bc[tid]));
  }
  __syncthreads();
  const float* wr = wf1 + (long long)tid * 1280;
  float a0 = 0.f, a1 = 0.f;
  for (int c = 0; c < 1024; c += 4) {
    const float4 w = *(const float4*)&wr[c];
    const float4 gv = *(const float4*)&gs[c];
    a0 = fmaf(w.x, gv.x, a0); a1 = fmaf(w.y, gv.y, a1);
    a0 = fmaf(w.z, gv.z, a0); a1 = fmaf(w.w, gv.w, a1);
  }
#pragma unroll
  for (int c = 0; c < 64; c += 4) {
    const float4 w = *(const float4*)&wr[1024 + c];
    const float4 cv = *(const float4*)&cvs[c];
    a0 = fmaf(w.x, cv.x, a0); a1 = fmaf(w.y, cv.y, a1);
    a0 = fmaf(w.z, cv.z, a0); a1 = fmaf(w.w, cv.w, a1);
  }
  tvec[b * 256 + tid] = a0 + a1;
}

// ---------------- logits + log_softmax ----------------
__global__ __launch_bounds__(256) void logits_k(const float* __restrict__ f3t, const float* __restrict__ wf4,
                                                float* __restrict__ out) {
  __shared__ float wT[6464];
  const int tid = threadIdx.x, lane = tid & 63, wv = tid >> 6;
  for (int q = tid; q < 6400; q += 256) {
    const int o = q >> 7, c = q & 127;
    wT[c * 50 + o] = wf4[q];
  }
  __syncthreads();
  const long long pn = (long long)blockIdx.x * 4 + wv;
  const float lo = f3t[pn * 128 + lane], hi = f3t[pn * 128 + 64 + lane];
  float a0 = 0.f, a1 = 0.f;
#pragma unroll
  for (int c = 0; c < 64; c += 2) {
    a0 = fmaf(wT[c * 50 + lane], rl(lo, c), a0);
    a1 = fmaf(wT[(c + 1) * 50 + lane], rl(lo, c + 1), a1);
  }
#pragma unroll
  for (int c = 0; c < 64; c += 2) {
    a0 = fmaf(wT[(64 + c) * 50 + lane], rl(hi, c), a0);
    a1 = fmaf(wT[(65 + c) * 50 + lane], rl(hi, c + 1), a1);
  }
  const float logit = (lane < 50) ? (a0 + a1) : -3.4e38f;
  float M = logit;
#pragma unroll
  for (int mask = 1; mask < 64; mask <<= 1) M = fmaxf(M, __shfl_xor(M, mask, 64));
  const float ex = (lane < 50) ? __expf(logit - M) : 0.f;
  float S = ex;
#pragma unroll
  for (int mask = 1; mask < 64; mask <<= 1) S += __shfl_xor(S, mask, 64);
  if (lane < 50) out[pn * 50 + lane] = logit - M - __logf(S);
}

extern "C" void kernel_launch(void* const* d_in, const int* in_sizes, int n_in,
                              void* d_out, int out_size, void* d_ws, size_t ws_size,
                              hipStream_t stream) {
  (void)in_sizes; (void)n_in; (void)out_size; (void)ws_size;
  const float* points = (const float*)d_in[0];
  const float* cls = (const float*)d_in[1];
  const float* w1 = (const float*)d_in[2];
  const float* s1 = (const float*)d_in[3];
  const float* b1 = (const float*)d_in[4];
  const float* w2 = (const float*)d_in[5];
  const float* s2 = (const float*)d_in[6];
  const float* b2 = (const float*)d_in[7];
  const float* w3 = (const float*)d_in[8];
  const float* s3 = (const float*)d_in[9];
  const float* b3 = (const float*)d_in[10];
  const float* w4 = (const float*)d_in[11];
  const float* s4 = (const float*)d_in[12];
  const float* b4 = (const float*)d_in[13];
  const float* w5 = (const float*)d_in[14];
  const float* s5 = (const float*)d_in[15];
  const float* b5 = (const float*)d_in[16];
  const float* w6 = (const float*)d_in[17];
  const float* s6 = (const float*)d_in[18];
  const float* b6 = (const float*)d_in[19];
  const float* wc = (const float*)d_in[20];
  const float* sc = (const float*)d_in[21];
  const float* bc = (const float*)d_in[22];
  const float* wf1 = (const float*)d_in[23];
  const float* sf1 = (const float*)d_in[24];
  const float* bf1 = (const float*)d_in[25];
  const float* wf2 = (const float*)d_in[26];
  const float* sf2 = (const float*)d_in[27];
  const float* bf2 = (const float*)d_in[28];
  const float* wf3 = (const float*)d_in[29];
  const float* sf3 = (const float*)d_in[30];
  const float* bf3 = (const float*)d_in[31];
  const float* wf4 = (const float*)d_in[32];
  float* out = (float*)d_out;
  float* ws = (float*)d_ws;

  // workspace (floats): x1c@0  x2c@2097152  x3c@4194304  f1c@8388608(..16777216)
  // PQf/f3t time-share f1c region; f2c aliases x*c (dead by then); aux @16777216+
  float* x1c = ws;
  float* x2c = ws + 2097152LL;
  float* x3c = ws + 4194304LL;
  float* f1c = ws + 8388608LL;
  float* f2c = ws;
  float* f3t = ws + 8388608LL;
  float* PQf = ws + 8388608LL;
  int* idx = (int*)(ws + 16777216LL);
  float* xxb = ws + 17432576LL;
  float* gpart = ws + 17465344LL;
  float* tvec = ws + 17743872LL;
  float* wc3 = ws + 17747968LL;
  float* sc3 = ws + 17756160LL;
  float* bc3 = ws + 17756288LL;
  float* wc5 = ws + 17756416LL;
  float* sc5 = ws + 17764608LL;
  float* bc5 = ws + 17764736LL;
  unsigned short* W2hi = (unsigned short*)(ws + 17764864LL);
  unsigned short* W2lo = (unsigned short*)(ws + 17766912LL);
  unsigned short* W4hi = (unsigned short*)(ws + 17768960LL);
  unsigned short* W4lo = (unsigned short*)(ws + 17771008LL);

  SrcTab tabX{{x1c, x2c, x3c, nullptr}, {64LL * PTS, 64LL * PTS, 64LL * PTS, 0}};
  SrcTab tabX1{{x1c, nullptr, nullptr, nullptr}, {64LL * PTS, 0, 0, 0}};
  SrcTab tabX2{{x2c, nullptr, nullptr, nullptr}, {64LL * PTS, 0, 0, 0}};
  SrcTab tabF1{{f1c, f1c + 64 * PTS, f1c + 128 * PTS, f1c + 192 * PTS},
               {256LL * PTS, 256LL * PTS, 256LL * PTS, 256LL * PTS}};
  SrcTab tabF2{{f2c, f2c + 64 * PTS, f2c + 128 * PTS, f2c + 192 * PTS},
               {256LL * PTS, 256LL * PTS, 256LL * PTS, 256LL * PTS}};

  prep_k<<<64, 256, 0, stream>>>(w3, s3, b3, w5, s5, b5, wc3, sc3, bc3, wc5, sc5, bc5);
  wsplit_k<<<32, 256, 0, stream>>>(w2, w4, W2hi, W2lo, W4hi, W4lo);

  // ---- kNN 1 (fused, f32 bitwise-exact) + edge1 (split-MFMA) ----
  xnorm_k<3><<<128, 256, 0, stream>>>(points, xxb);
  fknn4_k<3><<<dim3(512, 16), 256, 0, stream>>>(points, xxb, idx);
  pq1_k<<<8192, 256, 0, stream>>>(points, w1, s1, b1, PQf);
  edgemf_k<<<4096, 256, 0, stream>>>(PQf, idx, W2hi, W2lo, s2, b2, x1c);

  // ---- kNN 2 + edge2 (split-MFMA) ----
  xnorm_k<64><<<128, 256, 0, stream>>>(x1c, xxb);
  fknn4_k<64><<<dim3(512, 16), 256, 0, stream>>>(x1c, xxb, idx);
  mfgemm_k<3, 1><<<dim3(16, 1, 16), 256, 0, stream>>>(wc3, 64, 0, tabX1, 64, sc3, bc3, nullptr, PQf, 128);
  edgemf_k<<<4096, 256, 0, stream>>>(PQf, idx, W4hi, W4lo, s4, b4, x2c);

  // ---- kNN 3 + edge3 ----
  xnorm_k<64><<<128, 256, 0, stream>>>(x2c, xxb);
  fknn4_k<64><<<dim3(512, 16), 256, 0, stream>>>(x2c, xxb, idx);
  mfgemm_k<3, 1><<<dim3(16, 1, 16), 256, 0, stream>>>(wc5, 64, 0, tabX2, 64, sc5, bc5, nullptr, PQf, 128);
  edge3f_k<<<1024, 256, 0, stream>>>(PQf, idx, x3c);

  // ---- head (split-MFMA) ----
  mfgemm_k<1, 1><<<dim3(16, 8, 16), 256, 0, stream>>>(w6, 192, 0, tabX, 192, s6, b6, nullptr, gpart, 1024);
  tvec_k<<<16, 256, 0, stream>>>(cls, wc, sc, bc, gpart, wf1, tvec);
  mfgemm_k<0, 1><<<dim3(16, 2, 16), 256, 0, stream>>>(wf1, 1280, 1088, tabX, 192, sf1, bf1, tvec, f1c, 256);
  mfgemm_k<0, 1><<<dim3(16, 2, 16), 256, 0, stream>>>(wf2, 256, 0, tabF1, 256, sf2, bf2, nullptr, f2c, 256);
  mfgemm_k<2, 1><<<dim3(16, 1, 16), 256, 0, stream>>>(wf3, 256, 0, tabF2, 256, sf3, bf3, nullptr, f3t, 128);
  logits_k<<<8192, 256, 0, stream>>>(f3t, wf4, out);
}